// Round 4
// baseline (173.532 us; speedup 1.0000x reference)
//
#include <hip/hip_runtime.h>

#define T_SEQ 2048
#define BATCH 4
#define NH 16
#define FDIM 16
#define HDIM 64
#define HIDDEN 1024
#define TOK (BATCH * T_SEQ)      // 8192
#define CH 128
#define NCHUNK (T_SEQ / CH)      // 16
#define NBH (BATCH * NH)         // 64

// workspace offsets (float32 units)
#define QK_OFF   0u              // f32 [TOK, 512]  (Q cols 0..255, K cols 256..511)
#define VT_OFF   4194304u        // bf16 [NBH][64 v][2048 t]
#define SRAW_OFF 8388608u        // bf16 [NBH][NCHUNK][64 n][256 r]
#define SPRE_OFF 16777216u       // bf16 same layout (exclusive prefix)
#define MK_OFF   25165824u       // f32 [NBH][NCHUNK][256]
#define OAB_OFF  25427968u       // bf16 [TOK,1024]
#define WQKV_OFF 29622272u       // bf16 [1536,1024] (Wq rows 0-255, Wk 256-511, Wv 512-1535)
#define WO_OFF   30408704u       // bf16 [1024,1024]

typedef float f32x4 __attribute__((ext_vector_type(4)));
typedef short bf16x8 __attribute__((ext_vector_type(8)));
typedef unsigned short us8 __attribute__((ext_vector_type(8)));
typedef unsigned short us4 __attribute__((ext_vector_type(4)));
typedef unsigned int u32;

__device__ __forceinline__ unsigned short f2b(float f) {
  union { float f; unsigned u; } v; v.f = f;
  unsigned r = (v.u + 0x7FFFu + ((v.u >> 16) & 1u)) >> 16;
  return (unsigned short)r;
}
__device__ __forceinline__ float b2f(unsigned short h) {
  union { unsigned u; float f; } v; v.u = ((unsigned)h) << 16; return v.f;
}

__device__ __forceinline__ void gload_lds16(const void* g, void* l) {
  __builtin_amdgcn_global_load_lds(
      (const __attribute__((address_space(1))) u32*)g,
      (__attribute__((address_space(3))) u32*)l, 16, 0, 0);
}

// ---------------------------------------------------------------------------
// All weights -> bf16 in one kernel.
// WQKVB[1536,1024] from Wq|Wk|Wv; WOB[1024,1024] from Wo.
// ---------------------------------------------------------------------------
__global__ __launch_bounds__(256) void conv_w(const float* __restrict__ Wq,
                                              const float* __restrict__ Wk,
                                              const float* __restrict__ Wv,
                                              const float* __restrict__ Wo,
                                              unsigned short* __restrict__ WQKVB,
                                              unsigned short* __restrict__ WOB) {
  int i = blockIdx.x * 256 + threadIdx.x;  // 8-elt unit, total 327680
  const float* src;
  unsigned short* dst;
  if (i < 196608) {
    int f = i * 8;
    if (f < 262144)      { src = Wq + f;          }
    else if (f < 524288) { src = Wk + (f - 262144); }
    else                 { src = Wv + (f - 524288); }
    dst = WQKVB + f;
  } else {
    int f = (i - 196608) * 8;
    src = Wo + f; dst = WOB + f;
  }
  float4 v0 = *(const float4*)src, v1 = *(const float4*)(src + 4);
  us8 o;
  o[0] = f2b(v0.x); o[1] = f2b(v0.y); o[2] = f2b(v0.z); o[3] = f2b(v0.w);
  o[4] = f2b(v1.x); o[5] = f2b(v1.y); o[6] = f2b(v1.z); o[7] = f2b(v1.w);
  *(us8*)dst = o;
}

// ---------------------------------------------------------------------------
// Fused projection GEMM: A = hs f32 [8192,1024] (reg-staged -> bf16 LDS),
// W = WQKVB [1536,1024]. cols 0-511 -> QK (f32); cols 512-1535 -> V,
// written TRANSPOSED to VTg[bh][v][t] via LDS-staged coalesced stores.
// 128x128 tile, BK=64, 4 waves. Grid 768 (XCD-swizzled 1D).
// ---------------------------------------------------------------------------
__global__ __launch_bounds__(256) void proj_gemm(const float* __restrict__ hs,
                                                 const unsigned short* __restrict__ Wb,
                                                 float* __restrict__ QK,
                                                 unsigned short* __restrict__ VTg) {
  __shared__ unsigned short smem[17408];         // A[128][64] | B[128][64] ; reused as ct[128][136]
  unsigned short* Asl = smem;
  unsigned short* Bsl = smem + 8192;
  const int tid = threadIdx.x;
  const int lane = tid & 63, wid = tid >> 6;
  const int wr = wid >> 1, wc = wid & 1;
  const int ln = lane & 15, lg = lane >> 4;
  const int bid = blockIdx.x;
  const int logical = (bid & 7) * 96 + (bid >> 3);   // 768 % 8 == 0 -> bijective
  const int bx = logical & 63, by = logical >> 6;    // by in [0,12)
  const int m0 = bx * 128, n0 = by * 128;

  f32x4 acc[4][4];
#pragma unroll
  for (int m = 0; m < 4; ++m)
#pragma unroll
    for (int n = 0; n < 4; ++n) acc[m][n] = (f32x4){0.f, 0.f, 0.f, 0.f};

  const int srow = lane >> 3, skoff = (lane & 7) * 8;

  for (int k0 = 0; k0 < HIDDEN; k0 += 64) {
    // B: async global->LDS (bf16 weights)
#pragma unroll
    for (int i = 0; i < 4; ++i) {
      int ra = wid * 32 + i * 8;
      gload_lds16(&Wb[(size_t)(n0 + ra + srow) * HIDDEN + k0 + skoff], &Bsl[ra * 64]);
    }
    // A: reg-stage f32 -> bf16 -> LDS (fused convert)
#pragma unroll
    for (int it = 0; it < 8; ++it) {
      int fid = it * 256 + tid, row = fid >> 4, c4 = fid & 15;
      float4 a = *(const float4*)&hs[(size_t)(m0 + row) * HIDDEN + k0 + c4 * 4];
      us4 p; p[0] = f2b(a.x); p[1] = f2b(a.y); p[2] = f2b(a.z); p[3] = f2b(a.w);
      *(us4*)&Asl[row * 64 + c4 * 4] = p;
    }
    __syncthreads();
#pragma unroll
    for (int kk = 0; kk < 2; ++kk) {
      bf16x8 af[4], bf_[4];
#pragma unroll
      for (int m = 0; m < 4; ++m)
        af[m] = *(const bf16x8*)&Asl[(wr * 64 + m * 16 + ln) * 64 + kk * 32 + lg * 8];
#pragma unroll
      for (int n = 0; n < 4; ++n)
        bf_[n] = *(const bf16x8*)&Bsl[(wc * 64 + n * 16 + ln) * 64 + kk * 32 + lg * 8];
#pragma unroll
      for (int m = 0; m < 4; ++m)
#pragma unroll
        for (int n = 0; n < 4; ++n)
          acc[m][n] = __builtin_amdgcn_mfma_f32_16x16x32_bf16(af[m], bf_[n], acc[m][n], 0, 0, 0);
    }
    __syncthreads();
  }

  if (by < 4) {
    // QK path: f32 row-major [8192, 512]
#pragma unroll
    for (int m = 0; m < 4; ++m)
#pragma unroll
      for (int n = 0; n < 4; ++n) {
        int col = n0 + wc * 64 + n * 16 + ln;
        int row0 = m0 + wr * 64 + m * 16 + lg * 4;
#pragma unroll
        for (int j = 0; j < 4; ++j)
          QK[(size_t)(row0 + j) * 512 + col] = acc[m][n][j];
      }
  } else {
    // V path: stage transposed tile in LDS, then coalesced 16B stores along t
    unsigned short (*ct)[136] = (unsigned short(*)[136])smem;
#pragma unroll
    for (int m = 0; m < 4; ++m)
#pragma unroll
      for (int n = 0; n < 4; ++n) {
        int cl = wc * 64 + n * 16 + ln;          // local v col 0..127
        int r0 = wr * 64 + m * 16 + lg * 4;      // local t row
        us4 p;
#pragma unroll
        for (int j = 0; j < 4; ++j) p[j] = f2b(acc[m][n][j]);
        *(us4*)&ct[cl][r0] = p;
      }
    __syncthreads();
    const int vbase = n0 - 512;
    const int b = m0 >> 11, t0 = m0 & 2047;
#pragma unroll
    for (int it = 0; it < 8; ++it) {
      int sid = it * 256 + tid, vl = sid >> 4, tc = sid & 15;
      int vg = vbase + vl, h = vg >> 6, vd = vg & 63;
      us8 val = *(const us8*)&ct[vl][tc * 8];
      *(us8*)&VTg[(((size_t)(b * 16 + h) * 64 + vd) << 11) + t0 + tc * 8] = val;
    }
  }
}

// ---------------------------------------------------------------------------
// Output GEMM: C[m,n] = sum_k OAB[m,k]*WOB[n,k], f32 out. XCD-swizzled.
// ---------------------------------------------------------------------------
__global__ __launch_bounds__(256) void out_gemm(const unsigned short* __restrict__ A,
                                                const unsigned short* __restrict__ W,
                                                float* __restrict__ C) {
  __shared__ unsigned short Asl[128][64];
  __shared__ unsigned short Bsl[128][64];
  const int tid = threadIdx.x;
  const int lane = tid & 63, wid = tid >> 6;
  const int wr = wid >> 1, wc = wid & 1;
  const int bid = blockIdx.x;
  const int logical = (bid & 7) * 64 + (bid >> 3);   // 512 % 8 == 0 -> bijective
  const int bx = logical & 63, by = logical >> 6;
  const int m0 = bx * 128, n0 = by * 128;

  f32x4 acc[4][4];
#pragma unroll
  for (int m = 0; m < 4; ++m)
#pragma unroll
    for (int n = 0; n < 4; ++n) acc[m][n] = (f32x4){0.f, 0.f, 0.f, 0.f};

  const int srow = lane >> 3, skoff = (lane & 7) * 8;

  for (int k0 = 0; k0 < HIDDEN; k0 += 64) {
#pragma unroll
    for (int i = 0; i < 4; ++i) {
      int ra = wid * 32 + i * 8;
      gload_lds16(&A[(size_t)(m0 + ra + srow) * HIDDEN + k0 + skoff], &Asl[ra][0]);
      gload_lds16(&W[(size_t)(n0 + ra + srow) * HIDDEN + k0 + skoff], &Bsl[ra][0]);
    }
    __syncthreads();
#pragma unroll
    for (int kk = 0; kk < 2; ++kk) {
      bf16x8 af[4], bf_[4];
#pragma unroll
      for (int m = 0; m < 4; ++m)
        af[m] = *(const bf16x8*)&Asl[wr * 64 + m * 16 + (lane & 15)][kk * 32 + (lane >> 4) * 8];
#pragma unroll
      for (int n = 0; n < 4; ++n)
        bf_[n] = *(const bf16x8*)&Bsl[wc * 64 + n * 16 + (lane & 15)][kk * 32 + (lane >> 4) * 8];
#pragma unroll
      for (int m = 0; m < 4; ++m)
#pragma unroll
        for (int n = 0; n < 4; ++n)
          acc[m][n] = __builtin_amdgcn_mfma_f32_16x16x32_bf16(af[m], bf_[n], acc[m][n], 0, 0, 0);
    }
    __syncthreads();
  }

#pragma unroll
  for (int m = 0; m < 4; ++m)
#pragma unroll
    for (int n = 0; n < 4; ++n) {
      int col = n0 + wc * 64 + n * 16 + (lane & 15);
      int row0 = m0 + wr * 64 + m * 16 + (lane >> 4) * 4;
#pragma unroll
      for (int j = 0; j < 4; ++j)
        C[(size_t)(row0 + j) * 1024 + col] = acc[m][n][j];
    }
}

// ---------------------------------------------------------------------------
__device__ __forceinline__ void ln16(const float* __restrict__ src,
                                     const float* __restrict__ gamma,
                                     const float* __restrict__ beta,
                                     float* dst) {
  float x[16];
#pragma unroll
  for (int q = 0; q < 4; ++q) {
    float4 v = *(const float4*)(src + q * 4);
    x[q * 4 + 0] = v.x; x[q * 4 + 1] = v.y;
    x[q * 4 + 2] = v.z; x[q * 4 + 3] = v.w;
  }
  float mu = 0.f;
#pragma unroll
  for (int f = 0; f < 16; ++f) mu += x[f];
  mu *= 0.0625f;
  float var = 0.f;
#pragma unroll
  for (int f = 0; f < 16; ++f) { float d = x[f] - mu; var += d * d; }
  var *= 0.0625f;
  const float rs = rsqrtf(var + 1e-5f);
#pragma unroll
  for (int f = 0; f < 16; ++f) dst[f] = (x[f] - mu) * rs * gamma[f] + beta[f];
}

// ---------------------------------------------------------------------------
// Phase 1 (MFMA): S_raw_T[n][r] = sum_s kf[s][r] * V[s][n];  Mk gram (f32).
// ---------------------------------------------------------------------------
__global__ __launch_bounds__(256) void k_states(const float* __restrict__ QK,
                                                const unsigned short* __restrict__ VTg,
                                                const float* __restrict__ gamma,
                                                const float* __restrict__ beta,
                                                unsigned short* __restrict__ Sraw,
                                                float* __restrict__ Mk) {
  const int c = blockIdx.x, bh = blockIdx.y;
  const int b = bh >> 4, h = bh & 15;
  __shared__ float XKT[16][140];
  __shared__ unsigned short VT[64][152];
  const int tid = threadIdx.x;
  const int lane = tid & 63, wid = tid >> 6;
  const int ln = lane & 15, lg = lane >> 4;

  if (tid < 128) {
    float xr[16];
    ln16(QK + (size_t)(b * T_SEQ + c * CH + tid) * 512 + 256 + h * FDIM, gamma, beta, xr);
#pragma unroll
    for (int f = 0; f < 16; ++f) XKT[f][tid] = xr[f];
  }
#pragma unroll
  for (int it = 0; it < 4; ++it) {
    int flat = tid + it * 256; int v = flat >> 4, sb = flat & 15;
    *(us8*)&VT[v][sb * 8] = *(const us8*)&VTg[((size_t)bh * 64 + v) * T_SEQ + c * CH + sb * 8];
  }
  __syncthreads();

  {
    int i = tid >> 4, j = tid & 15;
    float m = 0.f;
    for (int cc = 0; cc < CH; ++cc) m += XKT[i][cc] * XKT[j][cc];
    Mk[((size_t)bh * NCHUNK + c) * 256 + tid] = m;
  }

  f32x4 acc[4][4];
#pragma unroll
  for (int m = 0; m < 4; ++m)
#pragma unroll
    for (int n = 0; n < 4; ++n) acc[m][n] = (f32x4){0.f, 0.f, 0.f, 0.f};

#pragma unroll
  for (int kt = 0; kt < 4; ++kt) {
    const int s0 = kt * 32 + lg * 8;
    bf16x8 bfr[4];
#pragma unroll
    for (int nt = 0; nt < 4; ++nt) bfr[nt] = *(const bf16x8*)&VT[nt * 16 + ln][s0];
#pragma unroll
    for (int mi = 0; mi < 4; ++mi) {
      const int iidx = wid * 4 + mi;
      float4 xi0 = *(const float4*)&XKT[iidx][s0];
      float4 xi1 = *(const float4*)&XKT[iidx][s0 + 4];
      float4 xj0 = *(const float4*)&XKT[ln][s0];
      float4 xj1 = *(const float4*)&XKT[ln][s0 + 4];
      bf16x8 afr;
      afr[0] = (short)f2b(xi0.x * xj0.x); afr[1] = (short)f2b(xi0.y * xj0.y);
      afr[2] = (short)f2b(xi0.z * xj0.z); afr[3] = (short)f2b(xi0.w * xj0.w);
      afr[4] = (short)f2b(xi1.x * xj1.x); afr[5] = (short)f2b(xi1.y * xj1.y);
      afr[6] = (short)f2b(xi1.z * xj1.z); afr[7] = (short)f2b(xi1.w * xj1.w);
#pragma unroll
      for (int nt = 0; nt < 4; ++nt)
        acc[mi][nt] = __builtin_amdgcn_mfma_f32_16x16x32_bf16(afr, bfr[nt], acc[mi][nt], 0, 0, 0);
    }
  }

  unsigned short* Sp = Sraw + ((size_t)bh * NCHUNK + c) * (64 * 256);
#pragma unroll
  for (int mi = 0; mi < 4; ++mi) {
    int r0 = (wid * 4 + mi) * 16 + lg * 4;
#pragma unroll
    for (int nt = 0; nt < 4; ++nt) {
      int n = nt * 16 + ln;
      us4 pk;
#pragma unroll
      for (int j = 0; j < 4; ++j) pk[j] = f2b(acc[mi][nt][j]);
      *(us4*)&Sp[(size_t)n * 256 + r0] = pk;
    }
  }
}

// ---------------------------------------------------------------------------
// Phase 2 merged: blockIdx.x<8 -> S prefix; ==8 -> Mk prefix.
// ---------------------------------------------------------------------------
__global__ __launch_bounds__(256) void k_prefix(const unsigned short* __restrict__ Sraw,
                                                unsigned short* __restrict__ Spre,
                                                float* __restrict__ Mk) {
  const int bh = blockIdx.y;
  if (blockIdx.x < 8) {
    const int e8 = blockIdx.x * 256 + threadIdx.x;
    size_t base = (size_t)bh * NCHUNK * 16384 + (size_t)e8 * 8;
    float run[8] = {0.f, 0.f, 0.f, 0.f, 0.f, 0.f, 0.f, 0.f};
    for (int cc = 0; cc < NCHUNK; ++cc) {
      us8 v = *(const us8*)&Sraw[base + (size_t)cc * 16384];
      us8 w;
#pragma unroll
      for (int q = 0; q < 8; ++q) w[q] = f2b(run[q]);
      *(us8*)&Spre[base + (size_t)cc * 16384] = w;
#pragma unroll
      for (int q = 0; q < 8; ++q) run[q] += b2f(v[q]);
    }
  } else {
    const int e = threadIdx.x;
    size_t base = (size_t)bh * NCHUNK * 256 + e;
    float run = 0.f;
    for (int c = 0; c < NCHUNK; ++c) {
      float v = Mk[base + (size_t)c * 256];
      Mk[base + (size_t)c * 256] = run;
      run += v;
    }
  }
}

// ---------------------------------------------------------------------------
// Phase 3 (MFMA): att = (XQ XK^T)^2/16 masked; o = att@V + qf@P; z in f32.
// ---------------------------------------------------------------------------
__global__ __launch_bounds__(256) void k_attn_out(const float* __restrict__ QK,
                                                  const unsigned short* __restrict__ VTg,
                                                  const float* __restrict__ gamma,
                                                  const float* __restrict__ beta,
                                                  const unsigned short* __restrict__ Spre,
                                                  const float* __restrict__ Mkp,
                                                  unsigned short* __restrict__ OAB) {
  const int c = blockIdx.x, bh = blockIdx.y;
  const int b = bh >> 4, h = bh & 15;
  __shared__ unsigned short XQb[128][40];
  __shared__ unsigned short XKb[128][40];
  __shared__ unsigned short attb[128 * 128];
  __shared__ unsigned short VT[64][152];
  __shared__ float mksh[256];
  const int tid = threadIdx.x;
  const int lane = tid & 63, wid = tid >> 6;
  const int ln = lane & 15, lg = lane >> 4;

  {
    int r = tid & 127;
    const float* src = QK + (size_t)(b * T_SEQ + c * CH + r) * 512 + (tid < 128 ? 0 : 256) + h * FDIM;
    unsigned short* dst = (tid < 128) ? &XQb[r][0] : &XKb[r][0];
    float xr[16];
    ln16(src, gamma, beta, xr);
    us8 lo, hi, z8;
#pragma unroll
    for (int q = 0; q < 8; ++q) { lo[q] = f2b(xr[q]); hi[q] = f2b(xr[8 + q]); z8[q] = 0; }
    *(us8*)&dst[0] = lo; *(us8*)&dst[8] = hi;
    *(us8*)&dst[16] = z8; *(us8*)&dst[24] = z8;
  }
#pragma unroll
  for (int it = 0; it < 4; ++it) {
    int flat = tid + it * 256; int v = flat >> 4, sb = flat & 15;
    *(us8*)&VT[v][sb * 8] = *(const us8*)&VTg[((size_t)bh * 64 + v) * T_SEQ + c * CH + sb * 8];
  }
  mksh[tid] = Mkp[((size_t)bh * NCHUNK + c) * 256 + tid];
  __syncthreads();

  const int tb = wid * 32;
  const f32x4 zero4 = {0.f, 0.f, 0.f, 0.f};

  bf16x8 aq0 = *(const bf16x8*)&XQb[tb + ln][lg * 8];
  bf16x8 aq1 = *(const bf16x8*)&XQb[tb + 16 + ln][lg * 8];
  float zin[2][4];
#pragma unroll
  for (int mt = 0; mt < 2; ++mt)
#pragma unroll
    for (int j = 0; j < 4; ++j) zin[mt][j] = 0.f;

#pragma unroll
  for (int nt = 0; nt < 8; ++nt) {
    bf16x8 bk = *(const bf16x8*)&XKb[nt * 16 + ln][lg * 8];
    f32x4 c0 = __builtin_amdgcn_mfma_f32_16x16x32_bf16(aq0, bk, zero4, 0, 0, 0);
    f32x4 c1 = __builtin_amdgcn_mfma_f32_16x16x32_bf16(aq1, bk, zero4, 0, 0, 0);
    int s = nt * 16 + ln;
#pragma unroll
    for (int j = 0; j < 4; ++j) {
      int t0 = tb + lg * 4 + j;
      float d0 = c0[j];
      float a0 = (s <= t0) ? d0 * d0 * 0.0625f : 0.f;
      zin[0][j] += a0;
      attb[t0 * 128 + (s ^ ((t0 & 7) << 3))] = f2b(a0);
      int t1 = t0 + 16;
      float d1 = c1[j];
      float a1 = (s <= t1) ? d1 * d1 * 0.0625f : 0.f;
      zin[1][j] += a1;
      attb[t1 * 128 + (s ^ ((t1 & 7) << 3))] = f2b(a1);
    }
  }
#pragma unroll
  for (int mt = 0; mt < 2; ++mt)
#pragma unroll
    for (int j = 0; j < 4; ++j) {
      float zz = zin[mt][j];
      zz += __shfl_xor(zz, 1, 64);
      zz += __shfl_xor(zz, 2, 64);
      zz += __shfl_xor(zz, 4, 64);
      zz += __shfl_xor(zz, 8, 64);
      zin[mt][j] = zz;
    }

  f32x4 o[2][4];
#pragma unroll
  for (int mt = 0; mt < 2; ++mt)
#pragma unroll
    for (int nt = 0; nt < 4; ++nt) o[mt][nt] = zero4;

#pragma unroll
  for (int kt = 0; kt < 4; ++kt) {
    int s0 = kt * 32 + lg * 8;
    bf16x8 a0 = *(const bf16x8*)&attb[(tb + ln) * 128 + (s0 ^ ((ln & 7) << 3))];
    bf16x8 a1 = *(const bf16x8*)&attb[(tb + 16 + ln) * 128 + (s0 ^ ((ln & 7) << 3))];
#pragma unroll
    for (int nt = 0; nt < 4; ++nt) {
      bf16x8 bv = *(const bf16x8*)&VT[nt * 16 + ln][s0];
      o[0][nt] = __builtin_amdgcn_mfma_f32_16x16x32_bf16(a0, bv, o[0][nt], 0, 0, 0);
      o[1][nt] = __builtin_amdgcn_mfma_f32_16x16x32_bf16(a1, bv, o[1][nt], 0, 0, 0);
    }
  }

  const unsigned short* Sp = Spre + ((size_t)bh * NCHUNK + c) * (64 * 256);
  bf16x8 xlo0 = *(const bf16x8*)&XQb[tb + ln][0];
  bf16x8 xhi0 = *(const bf16x8*)&XQb[tb + ln][8];
  bf16x8 xlo1 = *(const bf16x8*)&XQb[tb + 16 + ln][0];
  bf16x8 xhi1 = *(const bf16x8*)&XQb[tb + 16 + ln][8];
#pragma unroll
  for (int kt = 0; kt < 8; ++kt) {
    int i = kt * 2 + (lg >> 1);
    float xqi0 = b2f(XQb[tb + ln][i]) * 0.0625f;
    float xqi1 = b2f(XQb[tb + 16 + ln][i]) * 0.0625f;
    bf16x8 sel0 = (lg & 1) ? xhi0 : xlo0;
    bf16x8 sel1 = (lg & 1) ? xhi1 : xlo1;
    bf16x8 qa0, qa1;
#pragma unroll
    for (int jj = 0; jj < 8; ++jj) {
      qa0[jj] = (short)f2b(xqi0 * b2f((unsigned short)sel0[jj]));
      qa1[jj] = (short)f2b(xqi1 * b2f((unsigned short)sel1[jj]));
    }
    int r0 = kt * 32 + lg * 8;
#pragma unroll
    for (int nt = 0; nt < 4; ++nt) {
      bf16x8 bp = *(const bf16x8*)&Sp[(size_t)(nt * 16 + ln) * 256 + r0];
      o[0][nt] = __builtin_amdgcn_mfma_f32_16x16x32_bf16(qa0, bp, o[0][nt], 0, 0, 0);
      o[1][nt] = __builtin_amdgcn_mfma_f32_16x16x32_bf16(qa1, bp, o[1][nt], 0, 0, 0);
    }
  }

  float zi2[2][4];
#pragma unroll
  for (int mt = 0; mt < 2; ++mt)
#pragma unroll
    for (int j = 0; j < 4; ++j) {
      int t = tb + mt * 16 + lg * 4 + j;
      float xqi = b2f(XQb[t][ln]);
      float p = 0.f;
#pragma unroll
      for (int jm = 0; jm < 16; ++jm) p += b2f(XQb[t][jm]) * mksh[jm * 16 + ln];
      p *= xqi;
      p += __shfl_xor(p, 1, 64);
      p += __shfl_xor(p, 2, 64);
      p += __shfl_xor(p, 4, 64);
      p += __shfl_xor(p, 8, 64);
      zi2[mt][j] = p * 0.0625f;
    }

  unsigned short* ob = OAB + ((size_t)(b * T_SEQ + c * CH)) * 1024 + h * 64;
#pragma unroll
  for (int mt = 0; mt < 2; ++mt)
#pragma unroll
    for (int j = 0; j < 4; ++j) {
      int t = tb + mt * 16 + lg * 4 + j;
      float inv = 1.0f / (zin[mt][j] + zi2[mt][j] + 1e-10f);
#pragma unroll
      for (int nt = 0; nt < 4; ++nt)
        ob[(size_t)t * 1024 + nt * 16 + ln] = f2b(o[mt][nt][j] * inv);
    }
}

// ---------------------------------------------------------------------------
extern "C" void kernel_launch(void* const* d_in, const int* in_sizes, int n_in,
                              void* d_out, int out_size, void* d_ws, size_t ws_size,
                              hipStream_t stream) {
  const float* hs    = (const float*)d_in[0];
  const float* Wq    = (const float*)d_in[1];
  const float* Wk    = (const float*)d_in[2];
  const float* Wv    = (const float*)d_in[3];
  const float* Wo    = (const float*)d_in[4];
  const float* gamma = (const float*)d_in[5];
  const float* beta  = (const float*)d_in[6];
  float* out = (float*)d_out;
  float* ws  = (float*)d_ws;

  float* QK = ws + QK_OFF;
  unsigned short* VTg   = (unsigned short*)(ws + VT_OFF);
  unsigned short* Sraw  = (unsigned short*)(ws + SRAW_OFF);
  unsigned short* Spre  = (unsigned short*)(ws + SPRE_OFF);
  float* Mk = ws + MK_OFF;
  unsigned short* OAB   = (unsigned short*)(ws + OAB_OFF);
  unsigned short* WQKVB = (unsigned short*)(ws + WQKV_OFF);
  unsigned short* WOB   = (unsigned short*)(ws + WO_OFF);

  dim3 blk(256);
  conv_w<<<1280, blk, 0, stream>>>(Wq, Wk, Wv, Wo, WQKVB, WOB);
  proj_gemm<<<768, blk, 0, stream>>>(hs, WQKVB, QK, VTg);
  k_states<<<dim3(NCHUNK, NBH), blk, 0, stream>>>(QK, VTg, gamma, beta, Sraw, Mk);
  k_prefix<<<dim3(9, NBH), blk, 0, stream>>>(Sraw, Spre, Mk);
  k_attn_out<<<dim3(NCHUNK, NBH), blk, 0, stream>>>(QK, VTg, gamma, beta, Spre, Mk, OAB);
  out_gemm<<<512, blk, 0, stream>>>(OAB, WOB, out);
}

// Round 5
// 153.583 us; speedup vs baseline: 1.1299x; 1.1299x over previous
//
#include <hip/hip_runtime.h>

#define T_SEQ 2048
#define BATCH 4
#define NH 16
#define FDIM 16
#define HDIM 64
#define HIDDEN 1024
#define TOK (BATCH * T_SEQ)      // 8192
#define CH 128
#define NCHUNK (T_SEQ / CH)      // 16
#define NBH (BATCH * NH)         // 64

// workspace offsets (float32 units)
#define QK_OFF   0u              // f32 [TOK, 512]  (Q cols 0..255, K cols 256..511)
#define VT_OFF   4194304u        // bf16 [NBH][64 v][2048 t]
#define SRAW_OFF 8388608u        // bf16 [NBH][NCHUNK][64 n][256 r]
#define SPRE_OFF 16777216u       // bf16 same layout (exclusive prefix)
#define MK_OFF   25165824u       // f32 [NBH][NCHUNK][256]
#define OAB_OFF  25427968u       // bf16 [TOK,1024]
#define WQKV_OFF 29622272u       // bf16 [1536,1024] (Wq 0-255, Wk 256-511, Wv 512-1535)
#define WO_OFF   30408704u       // bf16 [1024,1024]
#define HSB_OFF  30932992u       // bf16 [TOK,1024]

typedef float f32x4 __attribute__((ext_vector_type(4)));
typedef short bf16x8 __attribute__((ext_vector_type(8)));
typedef unsigned short us8 __attribute__((ext_vector_type(8)));
typedef unsigned short us4 __attribute__((ext_vector_type(4)));
typedef unsigned int u32;

__device__ __forceinline__ unsigned short f2b(float f) {
  union { float f; unsigned u; } v; v.f = f;
  unsigned r = (v.u + 0x7FFFu + ((v.u >> 16) & 1u)) >> 16;
  return (unsigned short)r;
}
__device__ __forceinline__ float b2f(unsigned short h) {
  union { unsigned u; float f; } v; v.u = ((unsigned)h) << 16; return v.f;
}

__device__ __forceinline__ void gload_lds16(const void* g, void* l) {
  __builtin_amdgcn_global_load_lds(
      (const __attribute__((address_space(1))) u32*)g,
      (__attribute__((address_space(3))) u32*)l, 16, 0, 0);
}

// ---------------------------------------------------------------------------
// One convert kernel: hs -> HSB, Wq|Wk|Wv -> WQKVB, Wo -> WOB. 8 elts/thread.
// units: hs 1048576 | qkv 196608 | wo 131072  (grid 5376 x 256)
// ---------------------------------------------------------------------------
__global__ __launch_bounds__(256) void conv_all(const float* __restrict__ hs,
                                                const float* __restrict__ Wq,
                                                const float* __restrict__ Wk,
                                                const float* __restrict__ Wv,
                                                const float* __restrict__ Wo,
                                                unsigned short* __restrict__ HSB,
                                                unsigned short* __restrict__ WQKVB,
                                                unsigned short* __restrict__ WOB) {
  int i = blockIdx.x * 256 + threadIdx.x;
  const float* src;
  unsigned short* dst;
  if (i < 1048576) {
    int f = i * 8; src = hs + f; dst = HSB + f;
  } else if (i < 1245184) {
    int f = (i - 1048576) * 8;
    if (f < 262144)      src = Wq + f;
    else if (f < 524288) src = Wk + (f - 262144);
    else                 src = Wv + (f - 524288);
    dst = WQKVB + f;
  } else {
    int f = (i - 1245184) * 8;
    src = Wo + f; dst = WOB + f;
  }
  float4 v0 = *(const float4*)src, v1 = *(const float4*)(src + 4);
  us8 o;
  o[0] = f2b(v0.x); o[1] = f2b(v0.y); o[2] = f2b(v0.z); o[3] = f2b(v0.w);
  o[4] = f2b(v1.x); o[5] = f2b(v1.y); o[6] = f2b(v1.z); o[7] = f2b(v1.w);
  *(us8*)dst = o;
}

// ---------------------------------------------------------------------------
// Fused QKV projection GEMM (bf16 A): A=HSB [8192,1024], W=WQKVB [1536,1024].
// cols 0-511 -> QK (f32 row-major); cols 512-1535 -> V transposed to
// VTg[bh][v][t] via LDS-staged coalesced stores. Grid 768 = 64 bx * 12 by,
// XCD swizzle with N-FASTEST within each XCD (A-panels L2-resident).
// ---------------------------------------------------------------------------
__global__ __launch_bounds__(256) void proj_gemm(const unsigned short* __restrict__ A,
                                                 const unsigned short* __restrict__ Wb,
                                                 float* __restrict__ QK,
                                                 unsigned short* __restrict__ VTg) {
  __shared__ unsigned short smem[17408];  // A[128][64] | B[128][64]; reused as ct[128][136]
  unsigned short* Asl = smem;
  unsigned short* Bsl = smem + 8192;
  const int tid = threadIdx.x;
  const int lane = tid & 63, wid = tid >> 6;
  const int wr = wid >> 1, wc = wid & 1;
  const int ln = lane & 15, lg = lane >> 4;
  const int bid = blockIdx.x;
  const int logical = (bid & 7) * 96 + (bid >> 3);  // 768 % 8 == 0 -> bijective
  const int bx = logical / 12, by = logical % 12;   // N-fastest within XCD
  const int m0 = bx * 128, n0 = by * 128;

  f32x4 acc[4][4];
#pragma unroll
  for (int m = 0; m < 4; ++m)
#pragma unroll
    for (int n = 0; n < 4; ++n) acc[m][n] = (f32x4){0.f, 0.f, 0.f, 0.f};

  const int srow = lane >> 3, skoff = (lane & 7) * 8;

  for (int k0 = 0; k0 < HIDDEN; k0 += 64) {
#pragma unroll
    for (int i = 0; i < 4; ++i) {
      int ra = wid * 32 + i * 8;
      gload_lds16(&A[(size_t)(m0 + ra + srow) * HIDDEN + k0 + skoff], &Asl[ra * 64]);
      gload_lds16(&Wb[(size_t)(n0 + ra + srow) * HIDDEN + k0 + skoff], &Bsl[ra * 64]);
    }
    __syncthreads();
#pragma unroll
    for (int kk = 0; kk < 2; ++kk) {
      bf16x8 af[4], bf_[4];
#pragma unroll
      for (int m = 0; m < 4; ++m)
        af[m] = *(const bf16x8*)&Asl[(wr * 64 + m * 16 + ln) * 64 + kk * 32 + lg * 8];
#pragma unroll
      for (int n = 0; n < 4; ++n)
        bf_[n] = *(const bf16x8*)&Bsl[(wc * 64 + n * 16 + ln) * 64 + kk * 32 + lg * 8];
#pragma unroll
      for (int m = 0; m < 4; ++m)
#pragma unroll
        for (int n = 0; n < 4; ++n)
          acc[m][n] = __builtin_amdgcn_mfma_f32_16x16x32_bf16(af[m], bf_[n], acc[m][n], 0, 0, 0);
    }
    __syncthreads();
  }

  if (by < 4) {
    // QK path: f32 row-major [8192, 512]
#pragma unroll
    for (int m = 0; m < 4; ++m)
#pragma unroll
      for (int n = 0; n < 4; ++n) {
        int col = n0 + wc * 64 + n * 16 + ln;
        int row0 = m0 + wr * 64 + m * 16 + lg * 4;
#pragma unroll
        for (int j = 0; j < 4; ++j)
          QK[(size_t)(row0 + j) * 512 + col] = acc[m][n][j];
      }
  } else {
    // V path: stage transposed tile in LDS, then coalesced 16B stores along t
    __syncthreads();
    unsigned short (*ct)[136] = (unsigned short(*)[136])smem;
#pragma unroll
    for (int m = 0; m < 4; ++m)
#pragma unroll
      for (int n = 0; n < 4; ++n) {
        int cl = wc * 64 + n * 16 + ln;
        int r0 = wr * 64 + m * 16 + lg * 4;
        us4 p;
#pragma unroll
        for (int j = 0; j < 4; ++j) p[j] = f2b(acc[m][n][j]);
        *(us4*)&ct[cl][r0] = p;
      }
    __syncthreads();
    const int vbase = n0 - 512;
    const int b = m0 >> 11, t0 = m0 & 2047;
#pragma unroll
    for (int it = 0; it < 8; ++it) {
      int sid = it * 256 + tid, vl = sid >> 4, tc = sid & 15;
      int vg = vbase + vl, h = vg >> 6, vd = vg & 63;
      us8 val = *(const us8*)&ct[vl][tc * 8];
      *(us8*)&VTg[(((size_t)(b * 16 + h) * 64 + vd) << 11) + t0 + tc * 8] = val;
    }
  }
}

// ---------------------------------------------------------------------------
// Output GEMM: C[m,n] = sum_k OAB[m,k]*WOB[n,k], f32 out. N-fastest XCD swz.
// ---------------------------------------------------------------------------
__global__ __launch_bounds__(256) void out_gemm(const unsigned short* __restrict__ A,
                                                const unsigned short* __restrict__ W,
                                                float* __restrict__ C) {
  __shared__ unsigned short Asl[128][64];
  __shared__ unsigned short Bsl[128][64];
  const int tid = threadIdx.x;
  const int lane = tid & 63, wid = tid >> 6;
  const int wr = wid >> 1, wc = wid & 1;
  const int bid = blockIdx.x;
  const int logical = (bid & 7) * 64 + (bid >> 3);  // 512 % 8 == 0 -> bijective
  const int bx = logical >> 3, by = logical & 7;    // N-fastest within XCD
  const int m0 = bx * 128, n0 = by * 128;

  f32x4 acc[4][4];
#pragma unroll
  for (int m = 0; m < 4; ++m)
#pragma unroll
    for (int n = 0; n < 4; ++n) acc[m][n] = (f32x4){0.f, 0.f, 0.f, 0.f};

  const int srow = lane >> 3, skoff = (lane & 7) * 8;

  for (int k0 = 0; k0 < HIDDEN; k0 += 64) {
#pragma unroll
    for (int i = 0; i < 4; ++i) {
      int ra = wid * 32 + i * 8;
      gload_lds16(&A[(size_t)(m0 + ra + srow) * HIDDEN + k0 + skoff], &Asl[ra][0]);
      gload_lds16(&W[(size_t)(n0 + ra + srow) * HIDDEN + k0 + skoff], &Bsl[ra][0]);
    }
    __syncthreads();
#pragma unroll
    for (int kk = 0; kk < 2; ++kk) {
      bf16x8 af[4], bf_[4];
#pragma unroll
      for (int m = 0; m < 4; ++m)
        af[m] = *(const bf16x8*)&Asl[wr * 64 + m * 16 + (lane & 15)][kk * 32 + (lane >> 4) * 8];
#pragma unroll
      for (int n = 0; n < 4; ++n)
        bf_[n] = *(const bf16x8*)&Bsl[wc * 64 + n * 16 + (lane & 15)][kk * 32 + (lane >> 4) * 8];
#pragma unroll
      for (int m = 0; m < 4; ++m)
#pragma unroll
        for (int n = 0; n < 4; ++n)
          acc[m][n] = __builtin_amdgcn_mfma_f32_16x16x32_bf16(af[m], bf_[n], acc[m][n], 0, 0, 0);
    }
    __syncthreads();
  }

#pragma unroll
  for (int m = 0; m < 4; ++m)
#pragma unroll
    for (int n = 0; n < 4; ++n) {
      int col = n0 + wc * 64 + n * 16 + (lane & 15);
      int row0 = m0 + wr * 64 + m * 16 + (lane >> 4) * 4;
#pragma unroll
      for (int j = 0; j < 4; ++j)
        C[(size_t)(row0 + j) * 1024 + col] = acc[m][n][j];
    }
}

// ---------------------------------------------------------------------------
__device__ __forceinline__ void ln16(const float* __restrict__ src,
                                     const float* __restrict__ gamma,
                                     const float* __restrict__ beta,
                                     float* dst) {
  float x[16];
#pragma unroll
  for (int q = 0; q < 4; ++q) {
    float4 v = *(const float4*)(src + q * 4);
    x[q * 4 + 0] = v.x; x[q * 4 + 1] = v.y;
    x[q * 4 + 2] = v.z; x[q * 4 + 3] = v.w;
  }
  float mu = 0.f;
#pragma unroll
  for (int f = 0; f < 16; ++f) mu += x[f];
  mu *= 0.0625f;
  float var = 0.f;
#pragma unroll
  for (int f = 0; f < 16; ++f) { float d = x[f] - mu; var += d * d; }
  var *= 0.0625f;
  const float rs = rsqrtf(var + 1e-5f);
#pragma unroll
  for (int f = 0; f < 16; ++f) dst[f] = (x[f] - mu) * rs * gamma[f] + beta[f];
}

// ---------------------------------------------------------------------------
// Phase 1 (MFMA): S_raw_T[n][r] = sum_s kf[s][r] * V[s][n];  Mk gram (f32).
// ---------------------------------------------------------------------------
__global__ __launch_bounds__(256) void k_states(const float* __restrict__ QK,
                                                const unsigned short* __restrict__ VTg,
                                                const float* __restrict__ gamma,
                                                const float* __restrict__ beta,
                                                unsigned short* __restrict__ Sraw,
                                                float* __restrict__ Mk) {
  const int c = blockIdx.x, bh = blockIdx.y;
  const int b = bh >> 4, h = bh & 15;
  __shared__ float XKT[16][140];
  __shared__ unsigned short VT[64][152];
  const int tid = threadIdx.x;
  const int lane = tid & 63, wid = tid >> 6;
  const int ln = lane & 15, lg = lane >> 4;

  if (tid < 128) {
    float xr[16];
    ln16(QK + (size_t)(b * T_SEQ + c * CH + tid) * 512 + 256 + h * FDIM, gamma, beta, xr);
#pragma unroll
    for (int f = 0; f < 16; ++f) XKT[f][tid] = xr[f];
  }
#pragma unroll
  for (int it = 0; it < 4; ++it) {
    int flat = tid + it * 256; int v = flat >> 4, sb = flat & 15;
    *(us8*)&VT[v][sb * 8] = *(const us8*)&VTg[((size_t)bh * 64 + v) * T_SEQ + c * CH + sb * 8];
  }
  __syncthreads();

  {
    int i = tid >> 4, j = tid & 15;
    float m = 0.f;
    for (int cc = 0; cc < CH; ++cc) m += XKT[i][cc] * XKT[j][cc];
    Mk[((size_t)bh * NCHUNK + c) * 256 + tid] = m;
  }

  f32x4 acc[4][4];
#pragma unroll
  for (int m = 0; m < 4; ++m)
#pragma unroll
    for (int n = 0; n < 4; ++n) acc[m][n] = (f32x4){0.f, 0.f, 0.f, 0.f};

#pragma unroll
  for (int kt = 0; kt < 4; ++kt) {
    const int s0 = kt * 32 + lg * 8;
    bf16x8 bfr[4];
#pragma unroll
    for (int nt = 0; nt < 4; ++nt) bfr[nt] = *(const bf16x8*)&VT[nt * 16 + ln][s0];
#pragma unroll
    for (int mi = 0; mi < 4; ++mi) {
      const int iidx = wid * 4 + mi;
      float4 xi0 = *(const float4*)&XKT[iidx][s0];
      float4 xi1 = *(const float4*)&XKT[iidx][s0 + 4];
      float4 xj0 = *(const float4*)&XKT[ln][s0];
      float4 xj1 = *(const float4*)&XKT[ln][s0 + 4];
      bf16x8 afr;
      afr[0] = (short)f2b(xi0.x * xj0.x); afr[1] = (short)f2b(xi0.y * xj0.y);
      afr[2] = (short)f2b(xi0.z * xj0.z); afr[3] = (short)f2b(xi0.w * xj0.w);
      afr[4] = (short)f2b(xi1.x * xj1.x); afr[5] = (short)f2b(xi1.y * xj1.y);
      afr[6] = (short)f2b(xi1.z * xj1.z); afr[7] = (short)f2b(xi1.w * xj1.w);
#pragma unroll
      for (int nt = 0; nt < 4; ++nt)
        acc[mi][nt] = __builtin_amdgcn_mfma_f32_16x16x32_bf16(afr, bfr[nt], acc[mi][nt], 0, 0, 0);
    }
  }

  unsigned short* Sp = Sraw + ((size_t)bh * NCHUNK + c) * (64 * 256);
#pragma unroll
  for (int mi = 0; mi < 4; ++mi) {
    int r0 = (wid * 4 + mi) * 16 + lg * 4;
#pragma unroll
    for (int nt = 0; nt < 4; ++nt) {
      int n = nt * 16 + ln;
      us4 pk;
#pragma unroll
      for (int j = 0; j < 4; ++j) pk[j] = f2b(acc[mi][nt][j]);
      *(us4*)&Sp[(size_t)n * 256 + r0] = pk;
    }
  }
}

// ---------------------------------------------------------------------------
// Phase 2 merged: blockIdx.x<8 -> S prefix; ==8 -> Mk prefix.
// ---------------------------------------------------------------------------
__global__ __launch_bounds__(256) void k_prefix(const unsigned short* __restrict__ Sraw,
                                                unsigned short* __restrict__ Spre,
                                                float* __restrict__ Mk) {
  const int bh = blockIdx.y;
  if (blockIdx.x < 8) {
    const int e8 = blockIdx.x * 256 + threadIdx.x;
    size_t base = (size_t)bh * NCHUNK * 16384 + (size_t)e8 * 8;
    float run[8] = {0.f, 0.f, 0.f, 0.f, 0.f, 0.f, 0.f, 0.f};
    for (int cc = 0; cc < NCHUNK; ++cc) {
      us8 v = *(const us8*)&Sraw[base + (size_t)cc * 16384];
      us8 w;
#pragma unroll
      for (int q = 0; q < 8; ++q) w[q] = f2b(run[q]);
      *(us8*)&Spre[base + (size_t)cc * 16384] = w;
#pragma unroll
      for (int q = 0; q < 8; ++q) run[q] += b2f(v[q]);
    }
  } else {
    const int e = threadIdx.x;
    size_t base = (size_t)bh * NCHUNK * 256 + e;
    float run = 0.f;
    for (int c = 0; c < NCHUNK; ++c) {
      float v = Mk[base + (size_t)c * 256];
      Mk[base + (size_t)c * 256] = run;
      run += v;
    }
  }
}

// ---------------------------------------------------------------------------
// Phase 3 (MFMA): att = (XQ XK^T)^2/16 masked; o = att@V + qf@P; z in f32.
// ---------------------------------------------------------------------------
__global__ __launch_bounds__(256) void k_attn_out(const float* __restrict__ QK,
                                                  const unsigned short* __restrict__ VTg,
                                                  const float* __restrict__ gamma,
                                                  const float* __restrict__ beta,
                                                  const unsigned short* __restrict__ Spre,
                                                  const float* __restrict__ Mkp,
                                                  unsigned short* __restrict__ OAB) {
  const int c = blockIdx.x, bh = blockIdx.y;
  const int b = bh >> 4, h = bh & 15;
  __shared__ unsigned short XQb[128][40];
  __shared__ unsigned short XKb[128][40];
  __shared__ unsigned short attb[128 * 128];
  __shared__ unsigned short VT[64][152];
  __shared__ float mksh[256];
  const int tid = threadIdx.x;
  const int lane = tid & 63, wid = tid >> 6;
  const int ln = lane & 15, lg = lane >> 4;

  {
    int r = tid & 127;
    const float* src = QK + (size_t)(b * T_SEQ + c * CH + r) * 512 + (tid < 128 ? 0 : 256) + h * FDIM;
    unsigned short* dst = (tid < 128) ? &XQb[r][0] : &XKb[r][0];
    float xr[16];
    ln16(src, gamma, beta, xr);
    us8 lo, hi, z8;
#pragma unroll
    for (int q = 0; q < 8; ++q) { lo[q] = f2b(xr[q]); hi[q] = f2b(xr[8 + q]); z8[q] = 0; }
    *(us8*)&dst[0] = lo; *(us8*)&dst[8] = hi;
    *(us8*)&dst[16] = z8; *(us8*)&dst[24] = z8;
  }
#pragma unroll
  for (int it = 0; it < 4; ++it) {
    int flat = tid + it * 256; int v = flat >> 4, sb = flat & 15;
    *(us8*)&VT[v][sb * 8] = *(const us8*)&VTg[((size_t)bh * 64 + v) * T_SEQ + c * CH + sb * 8];
  }
  mksh[tid] = Mkp[((size_t)bh * NCHUNK + c) * 256 + tid];
  __syncthreads();

  const int tb = wid * 32;
  const f32x4 zero4 = {0.f, 0.f, 0.f, 0.f};

  bf16x8 aq0 = *(const bf16x8*)&XQb[tb + ln][lg * 8];
  bf16x8 aq1 = *(const bf16x8*)&XQb[tb + 16 + ln][lg * 8];
  float zin[2][4];
#pragma unroll
  for (int mt = 0; mt < 2; ++mt)
#pragma unroll
    for (int j = 0; j < 4; ++j) zin[mt][j] = 0.f;

#pragma unroll
  for (int nt = 0; nt < 8; ++nt) {
    bf16x8 bk = *(const bf16x8*)&XKb[nt * 16 + ln][lg * 8];
    f32x4 c0 = __builtin_amdgcn_mfma_f32_16x16x32_bf16(aq0, bk, zero4, 0, 0, 0);
    f32x4 c1 = __builtin_amdgcn_mfma_f32_16x16x32_bf16(aq1, bk, zero4, 0, 0, 0);
    int s = nt * 16 + ln;
#pragma unroll
    for (int j = 0; j < 4; ++j) {
      int t0 = tb + lg * 4 + j;
      float d0 = c0[j];
      float a0 = (s <= t0) ? d0 * d0 * 0.0625f : 0.f;
      zin[0][j] += a0;
      attb[t0 * 128 + (s ^ ((t0 & 7) << 3))] = f2b(a0);
      int t1 = t0 + 16;
      float d1 = c1[j];
      float a1 = (s <= t1) ? d1 * d1 * 0.0625f : 0.f;
      zin[1][j] += a1;
      attb[t1 * 128 + (s ^ ((t1 & 7) << 3))] = f2b(a1);
    }
  }
#pragma unroll
  for (int mt = 0; mt < 2; ++mt)
#pragma unroll
    for (int j = 0; j < 4; ++j) {
      float zz = zin[mt][j];
      zz += __shfl_xor(zz, 1, 64);
      zz += __shfl_xor(zz, 2, 64);
      zz += __shfl_xor(zz, 4, 64);
      zz += __shfl_xor(zz, 8, 64);
      zin[mt][j] = zz;
    }

  f32x4 o[2][4];
#pragma unroll
  for (int mt = 0; mt < 2; ++mt)
#pragma unroll
    for (int nt = 0; nt < 4; ++nt) o[mt][nt] = zero4;

#pragma unroll
  for (int kt = 0; kt < 4; ++kt) {
    int s0 = kt * 32 + lg * 8;
    bf16x8 a0 = *(const bf16x8*)&attb[(tb + ln) * 128 + (s0 ^ ((ln & 7) << 3))];
    bf16x8 a1 = *(const bf16x8*)&attb[(tb + 16 + ln) * 128 + (s0 ^ ((ln & 7) << 3))];
#pragma unroll
    for (int nt = 0; nt < 4; ++nt) {
      bf16x8 bv = *(const bf16x8*)&VT[nt * 16 + ln][s0];
      o[0][nt] = __builtin_amdgcn_mfma_f32_16x16x32_bf16(a0, bv, o[0][nt], 0, 0, 0);
      o[1][nt] = __builtin_amdgcn_mfma_f32_16x16x32_bf16(a1, bv, o[1][nt], 0, 0, 0);
    }
  }

  const unsigned short* Sp = Spre + ((size_t)bh * NCHUNK + c) * (64 * 256);
  bf16x8 xlo0 = *(const bf16x8*)&XQb[tb + ln][0];
  bf16x8 xhi0 = *(const bf16x8*)&XQb[tb + ln][8];
  bf16x8 xlo1 = *(const bf16x8*)&XQb[tb + 16 + ln][0];
  bf16x8 xhi1 = *(const bf16x8*)&XQb[tb + 16 + ln][8];
#pragma unroll
  for (int kt = 0; kt < 8; ++kt) {
    int i = kt * 2 + (lg >> 1);
    float xqi0 = b2f(XQb[tb + ln][i]) * 0.0625f;
    float xqi1 = b2f(XQb[tb + 16 + ln][i]) * 0.0625f;
    bf16x8 sel0 = (lg & 1) ? xhi0 : xlo0;
    bf16x8 sel1 = (lg & 1) ? xhi1 : xlo1;
    bf16x8 qa0, qa1;
#pragma unroll
    for (int jj = 0; jj < 8; ++jj) {
      qa0[jj] = (short)f2b(xqi0 * b2f((unsigned short)sel0[jj]));
      qa1[jj] = (short)f2b(xqi1 * b2f((unsigned short)sel1[jj]));
    }
    int r0 = kt * 32 + lg * 8;
#pragma unroll
    for (int nt = 0; nt < 4; ++nt) {
      bf16x8 bp = *(const bf16x8*)&Sp[(size_t)(nt * 16 + ln) * 256 + r0];
      o[0][nt] = __builtin_amdgcn_mfma_f32_16x16x32_bf16(qa0, bp, o[0][nt], 0, 0, 0);
      o[1][nt] = __builtin_amdgcn_mfma_f32_16x16x32_bf16(qa1, bp, o[1][nt], 0, 0, 0);
    }
  }

  float zi2[2][4];
#pragma unroll
  for (int mt = 0; mt < 2; ++mt)
#pragma unroll
    for (int j = 0; j < 4; ++j) {
      int t = tb + mt * 16 + lg * 4 + j;
      float xqi = b2f(XQb[t][ln]);
      float p = 0.f;
#pragma unroll
      for (int jm = 0; jm < 16; ++jm) p += b2f(XQb[t][jm]) * mksh[jm * 16 + ln];
      p *= xqi;
      p += __shfl_xor(p, 1, 64);
      p += __shfl_xor(p, 2, 64);
      p += __shfl_xor(p, 4, 64);
      p += __shfl_xor(p, 8, 64);
      zi2[mt][j] = p * 0.0625f;
    }

  unsigned short* ob = OAB + ((size_t)(b * T_SEQ + c * CH)) * 1024 + h * 64;
#pragma unroll
  for (int mt = 0; mt < 2; ++mt)
#pragma unroll
    for (int j = 0; j < 4; ++j) {
      int t = tb + mt * 16 + lg * 4 + j;
      float inv = 1.0f / (zin[mt][j] + zi2[mt][j] + 1e-10f);
#pragma unroll
      for (int nt = 0; nt < 4; ++nt)
        ob[(size_t)t * 1024 + nt * 16 + ln] = f2b(o[mt][nt][j] * inv);
    }
}

// ---------------------------------------------------------------------------
extern "C" void kernel_launch(void* const* d_in, const int* in_sizes, int n_in,
                              void* d_out, int out_size, void* d_ws, size_t ws_size,
                              hipStream_t stream) {
  const float* hs    = (const float*)d_in[0];
  const float* Wq    = (const float*)d_in[1];
  const float* Wk    = (const float*)d_in[2];
  const float* Wv    = (const float*)d_in[3];
  const float* Wo    = (const float*)d_in[4];
  const float* gamma = (const float*)d_in[5];
  const float* beta  = (const float*)d_in[6];
  float* out = (float*)d_out;
  float* ws  = (float*)d_ws;

  float* QK = ws + QK_OFF;
  unsigned short* VTg   = (unsigned short*)(ws + VT_OFF);
  unsigned short* Sraw  = (unsigned short*)(ws + SRAW_OFF);
  unsigned short* Spre  = (unsigned short*)(ws + SPRE_OFF);
  float* Mk = ws + MK_OFF;
  unsigned short* OAB   = (unsigned short*)(ws + OAB_OFF);
  unsigned short* WQKVB = (unsigned short*)(ws + WQKV_OFF);
  unsigned short* WOB   = (unsigned short*)(ws + WO_OFF);
  unsigned short* HSB   = (unsigned short*)(ws + HSB_OFF);

  dim3 blk(256);
  conv_all<<<5376, blk, 0, stream>>>(hs, Wq, Wk, Wv, Wo, HSB, WQKVB, WOB);
  proj_gemm<<<768, blk, 0, stream>>>(HSB, WQKVB, QK, VTg);
  k_states<<<dim3(NCHUNK, NBH), blk, 0, stream>>>(QK, VTg, gamma, beta, Sraw, Mk);
  k_prefix<<<dim3(9, NBH), blk, 0, stream>>>(Sraw, Spre, Mk);
  k_attn_out<<<dim3(NCHUNK, NBH), blk, 0, stream>>>(QK, VTg, gamma, beta, Spre, Mk, OAB);
  out_gemm<<<512, blk, 0, stream>>>(OAB, WOB, out);
}

// Round 6
// 137.651 us; speedup vs baseline: 1.2607x; 1.1157x over previous
//
#include <hip/hip_runtime.h>

#define T_SEQ 2048
#define BATCH 4
#define NH 16
#define FDIM 16
#define HDIM 64
#define HIDDEN 1024
#define TOK (BATCH * T_SEQ)      // 8192
#define CH 128
#define NCHUNK (T_SEQ / CH)      // 16
#define NBH (BATCH * NH)         // 64

// workspace offsets (float32 units)
#define QK_OFF   0u              // f32 [TOK, 512]  (Q cols 0..255, K cols 256..511)
#define VT_OFF   4194304u        // bf16 [NBH][64 v][2048 t]
#define SRAW_OFF 8388608u        // bf16 [NBH][NCHUNK][64 n][256 r]
#define SPRE_OFF 16777216u       // bf16 same layout (exclusive prefix)
#define MK_OFF   25165824u       // f32 [NBH][NCHUNK][256]
#define OAB_OFF  25427968u       // bf16 [TOK,1024]
#define WQKV_OFF 29622272u       // bf16 [1536,1024] (Wq 0-255, Wk 256-511, Wv 512-1535)
#define WO_OFF   30408704u       // bf16 [1024,1024]
#define HSB_OFF  30932992u       // bf16 [TOK,1024]

typedef float f32x4 __attribute__((ext_vector_type(4)));
typedef short bf16x8 __attribute__((ext_vector_type(8)));
typedef unsigned short us8 __attribute__((ext_vector_type(8)));
typedef unsigned short us4 __attribute__((ext_vector_type(4)));
typedef unsigned int u32;

__device__ __forceinline__ unsigned short f2b(float f) {
  union { float f; unsigned u; } v; v.f = f;
  unsigned r = (v.u + 0x7FFFu + ((v.u >> 16) & 1u)) >> 16;
  return (unsigned short)r;
}
__device__ __forceinline__ float b2f(unsigned short h) {
  union { unsigned u; float f; } v; v.u = ((unsigned)h) << 16; return v.f;
}

__device__ __forceinline__ void gload_lds16(const void* g, void* l) {
  __builtin_amdgcn_global_load_lds(
      (const __attribute__((address_space(1))) u32*)g,
      (__attribute__((address_space(3))) u32*)l, 16, 0, 0);
}

// ---------------------------------------------------------------------------
// One convert kernel: hs -> HSB, Wq|Wk|Wv -> WQKVB, Wo -> WOB. 8 elts/thread.
// ---------------------------------------------------------------------------
__global__ __launch_bounds__(256) void conv_all(const float* __restrict__ hs,
                                                const float* __restrict__ Wq,
                                                const float* __restrict__ Wk,
                                                const float* __restrict__ Wv,
                                                const float* __restrict__ Wo,
                                                unsigned short* __restrict__ HSB,
                                                unsigned short* __restrict__ WQKVB,
                                                unsigned short* __restrict__ WOB) {
  int i = blockIdx.x * 256 + threadIdx.x;
  const float* src;
  unsigned short* dst;
  if (i < 1048576) {
    int f = i * 8; src = hs + f; dst = HSB + f;
  } else if (i < 1245184) {
    int f = (i - 1048576) * 8;
    if (f < 262144)      src = Wq + f;
    else if (f < 524288) src = Wk + (f - 262144);
    else                 src = Wv + (f - 524288);
    dst = WQKVB + f;
  } else {
    int f = (i - 1245184) * 8;
    src = Wo + f; dst = WOB + f;
  }
  float4 v0 = *(const float4*)src, v1 = *(const float4*)(src + 4);
  us8 o;
  o[0] = f2b(v0.x); o[1] = f2b(v0.y); o[2] = f2b(v0.z); o[3] = f2b(v0.w);
  o[4] = f2b(v1.x); o[5] = f2b(v1.y); o[6] = f2b(v1.z); o[7] = f2b(v1.w);
  *(us8*)dst = o;
}

// ---------------------------------------------------------------------------
// Pipelined GEMM core: BM=128, BN=256, BK=64, 512 thr (8 waves 2x4), 3-deep
// LDS pipeline with counted vmcnt (T3+T4), XOR-swizzled LDS (T2, both sides:
// pre-swizzled global k-offset on STAGE + same XOR on ds_read), setprio (T5).
// LDS: A[3][128][64] + B[3][256][64] bf16 = 144 KiB.
// ---------------------------------------------------------------------------
#define LDSA(p) (lds + (p) * 8192)
#define LDSB(p) (lds + 24576 + (p) * 16384)

__device__ __forceinline__ void stage6(const unsigned short* __restrict__ A,
                                       const unsigned short* __restrict__ B,
                                       int m0, int n0, int kt,
                                       unsigned short* ldsA, unsigned short* ldsB,
                                       int w, int lrow, int kswz) {
  const int kc = kt * 64 + kswz;
#pragma unroll
  for (int i = 0; i < 2; ++i) {
    int c = i * 8 + w;
    gload_lds16(&A[(size_t)(m0 + c * 8 + lrow) * HIDDEN + kc], &ldsA[c * 512]);
  }
#pragma unroll
  for (int i = 0; i < 4; ++i) {
    int c = i * 8 + w;
    gload_lds16(&B[(size_t)(n0 + c * 8 + lrow) * HIDDEN + kc], &ldsB[c * 512]);
  }
}

__device__ __forceinline__ void compute_tile(const unsigned short* __restrict__ ldsA,
                                             const unsigned short* __restrict__ ldsB,
                                             int wm, int wn, int ln, int lg,
                                             f32x4 acc[4][4]) {
  const int swz = (ln & 7) << 3;
#pragma unroll
  for (int kk = 0; kk < 2; ++kk) {
    const int col = (kk * 32 + lg * 8) ^ swz;
    bf16x8 af[4], bfr[4];
#pragma unroll
    for (int fm = 0; fm < 4; ++fm)
      af[fm] = *(const bf16x8*)&ldsA[(wm * 64 + fm * 16 + ln) * 64 + col];
#pragma unroll
    for (int fn = 0; fn < 4; ++fn)
      bfr[fn] = *(const bf16x8*)&ldsB[(wn * 64 + fn * 16 + ln) * 64 + col];
    __builtin_amdgcn_s_setprio(1);
#pragma unroll
    for (int fm = 0; fm < 4; ++fm)
#pragma unroll
      for (int fn = 0; fn < 4; ++fn)
        acc[fm][fn] = __builtin_amdgcn_mfma_f32_16x16x32_bf16(af[fm], bfr[fn], acc[fm][fn], 0, 0, 0);
    __builtin_amdgcn_s_setprio(0);
  }
}

#define GEMM_PIPELINE(Aptr, Bptr)                                              \
  const int tid = threadIdx.x;                                                 \
  const int lane = tid & 63, w = tid >> 6;                                     \
  const int wm = w >> 2, wn = w & 3;                                           \
  const int ln = lane & 15, lg = lane >> 4;                                    \
  const int lrow = lane >> 3;                                                  \
  const int kswz = (((lane & 7) ^ ((lane >> 3) & 7)) * 8);                     \
  f32x4 acc[4][4];                                                             \
  _Pragma("unroll") for (int m = 0; m < 4; ++m)                                \
    _Pragma("unroll") for (int n = 0; n < 4; ++n)                              \
      acc[m][n] = (f32x4){0.f, 0.f, 0.f, 0.f};                                 \
  stage6(Aptr, Bptr, m0, n0, 0, LDSA(0), LDSB(0), w, lrow, kswz);              \
  stage6(Aptr, Bptr, m0, n0, 1, LDSA(1), LDSB(1), w, lrow, kswz);              \
  int cur = 0;                                                                 \
  for (int t = 0; t < 16; ++t) {                                               \
    if (t < 14) {                                                              \
      int sb = cur + 2; if (sb >= 3) sb -= 3;                                  \
      stage6(Aptr, Bptr, m0, n0, t + 2, LDSA(sb), LDSB(sb), w, lrow, kswz);    \
      asm volatile("s_waitcnt vmcnt(12)" ::: "memory");                        \
    } else if (t == 14) {                                                      \
      asm volatile("s_waitcnt vmcnt(6)" ::: "memory");                         \
    } else {                                                                   \
      asm volatile("s_waitcnt vmcnt(0)" ::: "memory");                         \
    }                                                                          \
    __builtin_amdgcn_s_barrier();                                              \
    asm volatile("" ::: "memory");                                             \
    compute_tile(LDSA(cur), LDSB(cur), wm, wn, ln, lg, acc);                   \
    asm volatile("" ::: "memory");                                             \
    __builtin_amdgcn_s_barrier();                                              \
    cur = cur + 1; if (cur == 3) cur = 0;                                      \
  }

// ---------------------------------------------------------------------------
// Fused QKV projection: A=HSB [8192,1024], W=WQKVB [1536,1024].
// by 0-1 -> QK f32 [8192,512]; by 2-5 -> V transposed to VTg[bh][v][t].
// Grid 384 = 64 bx * 6 by, bijective XCD swizzle, N-fastest within XCD.
// ---------------------------------------------------------------------------
__global__ __launch_bounds__(512) void proj_gemm(const unsigned short* __restrict__ A,
                                                 const unsigned short* __restrict__ Wb,
                                                 float* __restrict__ QK,
                                                 unsigned short* __restrict__ VTg) {
  __shared__ unsigned short lds[73728];
  const int bid = blockIdx.x;
  const int logical = (bid & 7) * 48 + (bid >> 3);  // 384 % 8 == 0
  const int bx = logical / 6, by = logical % 6;
  const int m0 = bx * 128, n0 = by * 256;

  GEMM_PIPELINE(A, Wb)

  if (by < 2) {
#pragma unroll
    for (int fm = 0; fm < 4; ++fm)
#pragma unroll
      for (int fn = 0; fn < 4; ++fn) {
        int col = n0 + wn * 64 + fn * 16 + ln;
        int row0 = m0 + wm * 64 + fm * 16 + lg * 4;
#pragma unroll
        for (int j = 0; j < 4; ++j)
          QK[(size_t)(row0 + j) * 512 + col] = acc[fm][fn][j];
      }
  } else {
    // stage transposed tile in LDS, then coalesced 16B stores along t
    unsigned short (*ct)[136] = (unsigned short(*)[136])lds;
#pragma unroll
    for (int fm = 0; fm < 4; ++fm)
#pragma unroll
      for (int fn = 0; fn < 4; ++fn) {
        int cl = wn * 64 + fn * 16 + ln;        // local v col 0..255
        int r0 = wm * 64 + fm * 16 + lg * 4;    // local t row 0..127
        us4 p;
#pragma unroll
        for (int j = 0; j < 4; ++j) p[j] = f2b(acc[fm][fn][j]);
        *(us4*)&ct[cl][r0] = p;
      }
    __builtin_amdgcn_s_barrier();
    asm volatile("" ::: "memory");
    const int vbase = n0 - 512;
    const int b = m0 >> 11, t0 = m0 & 2047;
#pragma unroll
    for (int it = 0; it < 8; ++it) {
      int sid = it * 512 + tid, vl = sid >> 4, tc = sid & 15;
      int vg = vbase + vl, h = vg >> 6, vd = vg & 63;
      us8 val = *(const us8*)&ct[vl][tc * 8];
      *(us8*)&VTg[(((size_t)(b * 16 + h) * 64 + vd) << 11) + t0 + tc * 8] = val;
    }
  }
}

// ---------------------------------------------------------------------------
// Output GEMM: C[8192,1024] f32. Grid 256 = 64 bx * 4 by, XCD-swizzled.
// ---------------------------------------------------------------------------
__global__ __launch_bounds__(512) void out_gemm(const unsigned short* __restrict__ A,
                                                const unsigned short* __restrict__ W,
                                                float* __restrict__ C) {
  __shared__ unsigned short lds[73728];
  const int bid = blockIdx.x;
  const int logical = (bid & 7) * 32 + (bid >> 3);  // 256 % 8 == 0
  const int bx = logical >> 2, by = logical & 3;
  const int m0 = bx * 128, n0 = by * 256;

  GEMM_PIPELINE(A, W)

#pragma unroll
  for (int fm = 0; fm < 4; ++fm)
#pragma unroll
    for (int fn = 0; fn < 4; ++fn) {
      int col = n0 + wn * 64 + fn * 16 + ln;
      int row0 = m0 + wm * 64 + fm * 16 + lg * 4;
#pragma unroll
      for (int j = 0; j < 4; ++j)
        C[(size_t)(row0 + j) * 1024 + col] = acc[fm][fn][j];
    }
}

// ---------------------------------------------------------------------------
__device__ __forceinline__ void ln16(const float* __restrict__ src,
                                     const float* __restrict__ gamma,
                                     const float* __restrict__ beta,
                                     float* dst) {
  float x[16];
#pragma unroll
  for (int q = 0; q < 4; ++q) {
    float4 v = *(const float4*)(src + q * 4);
    x[q * 4 + 0] = v.x; x[q * 4 + 1] = v.y;
    x[q * 4 + 2] = v.z; x[q * 4 + 3] = v.w;
  }
  float mu = 0.f;
#pragma unroll
  for (int f = 0; f < 16; ++f) mu += x[f];
  mu *= 0.0625f;
  float var = 0.f;
#pragma unroll
  for (int f = 0; f < 16; ++f) { float d = x[f] - mu; var += d * d; }
  var *= 0.0625f;
  const float rs = rsqrtf(var + 1e-5f);
#pragma unroll
  for (int f = 0; f < 16; ++f) dst[f] = (x[f] - mu) * rs * gamma[f] + beta[f];
}

// ---------------------------------------------------------------------------
// Phase 1 (MFMA): S_raw_T[n][r] = sum_s kf[s][r] * V[s][n];  Mk gram (f32).
// ---------------------------------------------------------------------------
__global__ __launch_bounds__(256) void k_states(const float* __restrict__ QK,
                                                const unsigned short* __restrict__ VTg,
                                                const float* __restrict__ gamma,
                                                const float* __restrict__ beta,
                                                unsigned short* __restrict__ Sraw,
                                                float* __restrict__ Mk) {
  const int c = blockIdx.x, bh = blockIdx.y;
  const int b = bh >> 4, h = bh & 15;
  __shared__ float XKT[16][140];
  __shared__ unsigned short VT[64][152];
  const int tid = threadIdx.x;
  const int lane = tid & 63, wid = tid >> 6;
  const int ln = lane & 15, lg = lane >> 4;

  if (tid < 128) {
    float xr[16];
    ln16(QK + (size_t)(b * T_SEQ + c * CH + tid) * 512 + 256 + h * FDIM, gamma, beta, xr);
#pragma unroll
    for (int f = 0; f < 16; ++f) XKT[f][tid] = xr[f];
  }
#pragma unroll
  for (int it = 0; it < 4; ++it) {
    int flat = tid + it * 256; int v = flat >> 4, sb = flat & 15;
    *(us8*)&VT[v][sb * 8] = *(const us8*)&VTg[((size_t)bh * 64 + v) * T_SEQ + c * CH + sb * 8];
  }
  __syncthreads();

  {
    int i = tid >> 4, j = tid & 15;
    float m = 0.f;
    for (int cc = 0; cc < CH; ++cc) m += XKT[i][cc] * XKT[j][cc];
    Mk[((size_t)bh * NCHUNK + c) * 256 + tid] = m;
  }

  f32x4 acc[4][4];
#pragma unroll
  for (int m = 0; m < 4; ++m)
#pragma unroll
    for (int n = 0; n < 4; ++n) acc[m][n] = (f32x4){0.f, 0.f, 0.f, 0.f};

#pragma unroll
  for (int kt = 0; kt < 4; ++kt) {
    const int s0 = kt * 32 + lg * 8;
    bf16x8 bfr[4];
#pragma unroll
    for (int nt = 0; nt < 4; ++nt) bfr[nt] = *(const bf16x8*)&VT[nt * 16 + ln][s0];
#pragma unroll
    for (int mi = 0; mi < 4; ++mi) {
      const int iidx = wid * 4 + mi;
      float4 xi0 = *(const float4*)&XKT[iidx][s0];
      float4 xi1 = *(const float4*)&XKT[iidx][s0 + 4];
      float4 xj0 = *(const float4*)&XKT[ln][s0];
      float4 xj1 = *(const float4*)&XKT[ln][s0 + 4];
      bf16x8 afr;
      afr[0] = (short)f2b(xi0.x * xj0.x); afr[1] = (short)f2b(xi0.y * xj0.y);
      afr[2] = (short)f2b(xi0.z * xj0.z); afr[3] = (short)f2b(xi0.w * xj0.w);
      afr[4] = (short)f2b(xi1.x * xj1.x); afr[5] = (short)f2b(xi1.y * xj1.y);
      afr[6] = (short)f2b(xi1.z * xj1.z); afr[7] = (short)f2b(xi1.w * xj1.w);
#pragma unroll
      for (int nt = 0; nt < 4; ++nt)
        acc[mi][nt] = __builtin_amdgcn_mfma_f32_16x16x32_bf16(afr, bfr[nt], acc[mi][nt], 0, 0, 0);
    }
  }

  unsigned short* Sp = Sraw + ((size_t)bh * NCHUNK + c) * (64 * 256);
#pragma unroll
  for (int mi = 0; mi < 4; ++mi) {
    int r0 = (wid * 4 + mi) * 16 + lg * 4;
#pragma unroll
    for (int nt = 0; nt < 4; ++nt) {
      int n = nt * 16 + ln;
      us4 pk;
#pragma unroll
      for (int j = 0; j < 4; ++j) pk[j] = f2b(acc[mi][nt][j]);
      *(us4*)&Sp[(size_t)n * 256 + r0] = pk;
    }
  }
}

// ---------------------------------------------------------------------------
// Phase 2 merged: blockIdx.x<8 -> S prefix; ==8 -> Mk prefix.
// ---------------------------------------------------------------------------
__global__ __launch_bounds__(256) void k_prefix(const unsigned short* __restrict__ Sraw,
                                                unsigned short* __restrict__ Spre,
                                                float* __restrict__ Mk) {
  const int bh = blockIdx.y;
  if (blockIdx.x < 8) {
    const int e8 = blockIdx.x * 256 + threadIdx.x;
    size_t base = (size_t)bh * NCHUNK * 16384 + (size_t)e8 * 8;
    float run[8] = {0.f, 0.f, 0.f, 0.f, 0.f, 0.f, 0.f, 0.f};
    for (int cc = 0; cc < NCHUNK; ++cc) {
      us8 v = *(const us8*)&Sraw[base + (size_t)cc * 16384];
      us8 w;
#pragma unroll
      for (int q = 0; q < 8; ++q) w[q] = f2b(run[q]);
      *(us8*)&Spre[base + (size_t)cc * 16384] = w;
#pragma unroll
      for (int q = 0; q < 8; ++q) run[q] += b2f(v[q]);
    }
  } else {
    const int e = threadIdx.x;
    size_t base = (size_t)bh * NCHUNK * 256 + e;
    float run = 0.f;
    for (int c = 0; c < NCHUNK; ++c) {
      float v = Mk[base + (size_t)c * 256];
      Mk[base + (size_t)c * 256] = run;
      run += v;
    }
  }
}

// ---------------------------------------------------------------------------
// Phase 3 (MFMA): att = (XQ XK^T)^2/16 masked; o = att@V + qf@P; z in f32.
// ---------------------------------------------------------------------------
__global__ __launch_bounds__(256) void k_attn_out(const float* __restrict__ QK,
                                                  const unsigned short* __restrict__ VTg,
                                                  const float* __restrict__ gamma,
                                                  const float* __restrict__ beta,
                                                  const unsigned short* __restrict__ Spre,
                                                  const float* __restrict__ Mkp,
                                                  unsigned short* __restrict__ OAB) {
  const int c = blockIdx.x, bh = blockIdx.y;
  const int b = bh >> 4, h = bh & 15;
  __shared__ unsigned short XQb[128][40];
  __shared__ unsigned short XKb[128][40];
  __shared__ unsigned short attb[128 * 128];
  __shared__ unsigned short VT[64][152];
  __shared__ float mksh[256];
  const int tid = threadIdx.x;
  const int lane = tid & 63, wid = tid >> 6;
  const int ln = lane & 15, lg = lane >> 4;

  {
    int r = tid & 127;
    const float* src = QK + (size_t)(b * T_SEQ + c * CH + r) * 512 + (tid < 128 ? 0 : 256) + h * FDIM;
    unsigned short* dst = (tid < 128) ? &XQb[r][0] : &XKb[r][0];
    float xr[16];
    ln16(src, gamma, beta, xr);
    us8 lo, hi, z8;
#pragma unroll
    for (int q = 0; q < 8; ++q) { lo[q] = f2b(xr[q]); hi[q] = f2b(xr[8 + q]); z8[q] = 0; }
    *(us8*)&dst[0] = lo; *(us8*)&dst[8] = hi;
    *(us8*)&dst[16] = z8; *(us8*)&dst[24] = z8;
  }
#pragma unroll
  for (int it = 0; it < 4; ++it) {
    int flat = tid + it * 256; int v = flat >> 4, sb = flat & 15;
    *(us8*)&VT[v][sb * 8] = *(const us8*)&VTg[((size_t)bh * 64 + v) * T_SEQ + c * CH + sb * 8];
  }
  mksh[tid] = Mkp[((size_t)bh * NCHUNK + c) * 256 + tid];
  __syncthreads();

  const int tb = wid * 32;
  const f32x4 zero4 = {0.f, 0.f, 0.f, 0.f};

  bf16x8 aq0 = *(const bf16x8*)&XQb[tb + ln][lg * 8];
  bf16x8 aq1 = *(const bf16x8*)&XQb[tb + 16 + ln][lg * 8];
  float zin[2][4];
#pragma unroll
  for (int mt = 0; mt < 2; ++mt)
#pragma unroll
    for (int j = 0; j < 4; ++j) zin[mt][j] = 0.f;

#pragma unroll
  for (int nt = 0; nt < 8; ++nt) {
    bf16x8 bk = *(const bf16x8*)&XKb[nt * 16 + ln][lg * 8];
    f32x4 c0 = __builtin_amdgcn_mfma_f32_16x16x32_bf16(aq0, bk, zero4, 0, 0, 0);
    f32x4 c1 = __builtin_amdgcn_mfma_f32_16x16x32_bf16(aq1, bk, zero4, 0, 0, 0);
    int s = nt * 16 + ln;
#pragma unroll
    for (int j = 0; j < 4; ++j) {
      int t0 = tb + lg * 4 + j;
      float d0 = c0[j];
      float a0 = (s <= t0) ? d0 * d0 * 0.0625f : 0.f;
      zin[0][j] += a0;
      attb[t0 * 128 + (s ^ ((t0 & 7) << 3))] = f2b(a0);
      int t1 = t0 + 16;
      float d1 = c1[j];
      float a1 = (s <= t1) ? d1 * d1 * 0.0625f : 0.f;
      zin[1][j] += a1;
      attb[t1 * 128 + (s ^ ((t1 & 7) << 3))] = f2b(a1);
    }
  }
#pragma unroll
  for (int mt = 0; mt < 2; ++mt)
#pragma unroll
    for (int j = 0; j < 4; ++j) {
      float zz = zin[mt][j];
      zz += __shfl_xor(zz, 1, 64);
      zz += __shfl_xor(zz, 2, 64);
      zz += __shfl_xor(zz, 4, 64);
      zz += __shfl_xor(zz, 8, 64);
      zin[mt][j] = zz;
    }

  f32x4 o[2][4];
#pragma unroll
  for (int mt = 0; mt < 2; ++mt)
#pragma unroll
    for (int nt = 0; nt < 4; ++nt) o[mt][nt] = zero4;

#pragma unroll
  for (int kt = 0; kt < 4; ++kt) {
    int s0 = kt * 32 + lg * 8;
    bf16x8 a0 = *(const bf16x8*)&attb[(tb + ln) * 128 + (s0 ^ ((ln & 7) << 3))];
    bf16x8 a1 = *(const bf16x8*)&attb[(tb + 16 + ln) * 128 + (s0 ^ ((ln & 7) << 3))];
#pragma unroll
    for (int nt = 0; nt < 4; ++nt) {
      bf16x8 bv = *(const bf16x8*)&VT[nt * 16 + ln][s0];
      o[0][nt] = __builtin_amdgcn_mfma_f32_16x16x32_bf16(a0, bv, o[0][nt], 0, 0, 0);
      o[1][nt] = __builtin_amdgcn_mfma_f32_16x16x32_bf16(a1, bv, o[1][nt], 0, 0, 0);
    }
  }

  const unsigned short* Sp = Spre + ((size_t)bh * NCHUNK + c) * (64 * 256);
  bf16x8 xlo0 = *(const bf16x8*)&XQb[tb + ln][0];
  bf16x8 xhi0 = *(const bf16x8*)&XQb[tb + ln][8];
  bf16x8 xlo1 = *(const bf16x8*)&XQb[tb + 16 + ln][0];
  bf16x8 xhi1 = *(const bf16x8*)&XQb[tb + 16 + ln][8];
#pragma unroll
  for (int kt = 0; kt < 8; ++kt) {
    int i = kt * 2 + (lg >> 1);
    float xqi0 = b2f(XQb[tb + ln][i]) * 0.0625f;
    float xqi1 = b2f(XQb[tb + 16 + ln][i]) * 0.0625f;
    bf16x8 sel0 = (lg & 1) ? xhi0 : xlo0;
    bf16x8 sel1 = (lg & 1) ? xhi1 : xlo1;
    bf16x8 qa0, qa1;
#pragma unroll
    for (int jj = 0; jj < 8; ++jj) {
      qa0[jj] = (short)f2b(xqi0 * b2f((unsigned short)sel0[jj]));
      qa1[jj] = (short)f2b(xqi1 * b2f((unsigned short)sel1[jj]));
    }
    int r0 = kt * 32 + lg * 8;
#pragma unroll
    for (int nt = 0; nt < 4; ++nt) {
      bf16x8 bp = *(const bf16x8*)&Sp[(size_t)(nt * 16 + ln) * 256 + r0];
      o[0][nt] = __builtin_amdgcn_mfma_f32_16x16x32_bf16(qa0, bp, o[0][nt], 0, 0, 0);
      o[1][nt] = __builtin_amdgcn_mfma_f32_16x16x32_bf16(qa1, bp, o[1][nt], 0, 0, 0);
    }
  }

  float zi2[2][4];
#pragma unroll
  for (int mt = 0; mt < 2; ++mt)
#pragma unroll
    for (int j = 0; j < 4; ++j) {
      int t = tb + mt * 16 + lg * 4 + j;
      float xqi = b2f(XQb[t][ln]);
      float p = 0.f;
#pragma unroll
      for (int jm = 0; jm < 16; ++jm) p += b2f(XQb[t][jm]) * mksh[jm * 16 + ln];
      p *= xqi;
      p += __shfl_xor(p, 1, 64);
      p += __shfl_xor(p, 2, 64);
      p += __shfl_xor(p, 4, 64);
      p += __shfl_xor(p, 8, 64);
      zi2[mt][j] = p * 0.0625f;
    }

  unsigned short* ob = OAB + ((size_t)(b * T_SEQ + c * CH)) * 1024 + h * 64;
#pragma unroll
  for (int mt = 0; mt < 2; ++mt)
#pragma unroll
    for (int j = 0; j < 4; ++j) {
      int t = tb + mt * 16 + lg * 4 + j;
      float inv = 1.0f / (zin[mt][j] + zi2[mt][j] + 1e-10f);
#pragma unroll
      for (int nt = 0; nt < 4; ++nt)
        ob[(size_t)t * 1024 + nt * 16 + ln] = f2b(o[mt][nt][j] * inv);
    }
}

// ---------------------------------------------------------------------------
extern "C" void kernel_launch(void* const* d_in, const int* in_sizes, int n_in,
                              void* d_out, int out_size, void* d_ws, size_t ws_size,
                              hipStream_t stream) {
  const float* hs    = (const float*)d_in[0];
  const float* Wq    = (const float*)d_in[1];
  const float* Wk    = (const float*)d_in[2];
  const float* Wv    = (const float*)d_in[3];
  const float* Wo    = (const float*)d_in[4];
  const float* gamma = (const float*)d_in[5];
  const float* beta  = (const float*)d_in[6];
  float* out = (float*)d_out;
  float* ws  = (float*)d_ws;

  float* QK = ws + QK_OFF;
  unsigned short* VTg   = (unsigned short*)(ws + VT_OFF);
  unsigned short* Sraw  = (unsigned short*)(ws + SRAW_OFF);
  unsigned short* Spre  = (unsigned short*)(ws + SPRE_OFF);
  float* Mk = ws + MK_OFF;
  unsigned short* OAB   = (unsigned short*)(ws + OAB_OFF);
  unsigned short* WQKVB = (unsigned short*)(ws + WQKV_OFF);
  unsigned short* WOB   = (unsigned short*)(ws + WO_OFF);
  unsigned short* HSB   = (unsigned short*)(ws + HSB_OFF);

  dim3 blk(256);
  conv_all<<<5376, blk, 0, stream>>>(hs, Wq, Wk, Wv, Wo, HSB, WQKVB, WOB);
  proj_gemm<<<384, dim3(512), 0, stream>>>(HSB, WQKVB, QK, VTg);
  k_states<<<dim3(NCHUNK, NBH), blk, 0, stream>>>(QK, VTg, gamma, beta, Sraw, Mk);
  k_prefix<<<dim3(9, NBH), blk, 0, stream>>>(Sraw, Spre, Mk);
  k_attn_out<<<dim3(NCHUNK, NBH), blk, 0, stream>>>(QK, VTg, gamma, beta, Spre, Mk, OAB);
  out_gemm<<<256, dim3(512), 0, stream>>>(OAB, WOB, out);
}

// Round 7
// 137.572 us; speedup vs baseline: 1.2614x; 1.0006x over previous
//
#include <hip/hip_runtime.h>

#define T_SEQ 2048
#define BATCH 4
#define NH 16
#define FDIM 16
#define HDIM 64
#define HIDDEN 1024
#define TOK (BATCH * T_SEQ)      // 8192
#define CH 128
#define NCHUNK (T_SEQ / CH)      // 16
#define NBH (BATCH * NH)         // 64

// workspace offsets (float32 units)
#define QK_OFF   0u              // f32 [TOK, 512]  (Q cols 0..255, K cols 256..511)
#define VT_OFF   4194304u        // bf16 [NBH][64 v][2048 t]
#define SRAW_OFF 8388608u        // bf16 [NBH][NCHUNK][64 n][256 r]
#define SPRE_OFF 16777216u       // bf16 same layout (exclusive prefix)
#define MK_OFF   25165824u       // f32 [NBH][NCHUNK][256]
#define OAB_OFF  25427968u       // bf16 [TOK,1024]
#define WQKV_OFF 29622272u       // bf16 [1536,1024] (Wq 0-255, Wk 256-511, Wv 512-1535)
#define WO_OFF   30408704u       // bf16 [1024,1024]
#define HSB_OFF  30932992u       // bf16 [TOK,1024]

typedef float f32x4 __attribute__((ext_vector_type(4)));
typedef short bf16x8 __attribute__((ext_vector_type(8)));
typedef unsigned short us8 __attribute__((ext_vector_type(8)));
typedef unsigned short us4 __attribute__((ext_vector_type(4)));
typedef unsigned int u32;

__device__ __forceinline__ unsigned short f2b(float f) {
  union { float f; unsigned u; } v; v.f = f;
  unsigned r = (v.u + 0x7FFFu + ((v.u >> 16) & 1u)) >> 16;
  return (unsigned short)r;
}
__device__ __forceinline__ float b2f(unsigned short h) {
  union { unsigned u; float f; } v; v.u = ((unsigned)h) << 16; return v.f;
}

__device__ __forceinline__ void gload_lds16(const void* g, void* l) {
  __builtin_amdgcn_global_load_lds(
      (const __attribute__((address_space(1))) u32*)g,
      (__attribute__((address_space(3))) u32*)l, 16, 0, 0);
}

// ---------------------------------------------------------------------------
// One convert kernel: hs -> HSB, Wq|Wk|Wv -> WQKVB, Wo -> WOB. 8 elts/thread.
// ---------------------------------------------------------------------------
__global__ __launch_bounds__(256) void conv_all(const float* __restrict__ hs,
                                                const float* __restrict__ Wq,
                                                const float* __restrict__ Wk,
                                                const float* __restrict__ Wv,
                                                const float* __restrict__ Wo,
                                                unsigned short* __restrict__ HSB,
                                                unsigned short* __restrict__ WQKVB,
                                                unsigned short* __restrict__ WOB) {
  int i = blockIdx.x * 256 + threadIdx.x;
  const float* src;
  unsigned short* dst;
  if (i < 1048576) {
    int f = i * 8; src = hs + f; dst = HSB + f;
  } else if (i < 1245184) {
    int f = (i - 1048576) * 8;
    if (f < 262144)      src = Wq + f;
    else if (f < 524288) src = Wk + (f - 262144);
    else                 src = Wv + (f - 524288);
    dst = WQKVB + f;
  } else {
    int f = (i - 1245184) * 8;
    src = Wo + f; dst = WOB + f;
  }
  float4 v0 = *(const float4*)src, v1 = *(const float4*)(src + 4);
  us8 o;
  o[0] = f2b(v0.x); o[1] = f2b(v0.y); o[2] = f2b(v0.z); o[3] = f2b(v0.w);
  o[4] = f2b(v1.x); o[5] = f2b(v1.y); o[6] = f2b(v1.z); o[7] = f2b(v1.w);
  *(us8*)dst = o;
}

// ---------------------------------------------------------------------------
// 8-phase-style pipelined GEMM core: BM=128, BN=256, BK=64, 512 thr (8 waves
// 2Mx4N, per-wave 64x64). 3-deep LDS (144 KiB). Per K-tile: 4 phases, each
// {ds_read quadrant ops | issue slice of tile t+2 staging | barrier |
//  setprio+8 MFMA+setprio | barrier}; ONE counted vmcnt(6) per K-tile (P3)
// validating tile t+1 -- never drains to 0 until epilogue (T3+T4). T2 swizzle
// both-sides (pre-swizzled global k-offset + XOR on read). T5 setprio.
// ---------------------------------------------------------------------------
#define LDSA(p) (lds + (p) * 8192)
#define LDSB(p) (lds + 24576 + (p) * 16384)

__device__ __forceinline__ void stageA2(const unsigned short* __restrict__ A,
                                        int m0, int kt, unsigned short* ldsA,
                                        int w, int lrow, int kswz) {
  const int kc = kt * 64 + kswz;
  gload_lds16(&A[(size_t)(m0 + w * 8 + lrow) * HIDDEN + kc], &ldsA[w * 512]);
  gload_lds16(&A[(size_t)(m0 + 64 + w * 8 + lrow) * HIDDEN + kc], &ldsA[(8 + w) * 512]);
}
__device__ __forceinline__ void stageB1(const unsigned short* __restrict__ B,
                                        int n0, int kt, unsigned short* ldsB,
                                        int i, int w, int lrow, int kswz) {
  const int kc = kt * 64 + kswz;
  const int c = i * 8 + w;
  gload_lds16(&B[(size_t)(n0 + c * 8 + lrow) * HIDDEN + kc], &ldsB[c * 512]);
}

#define BARF() do { asm volatile("" ::: "memory"); __builtin_amdgcn_s_barrier(); \
                    asm volatile("" ::: "memory"); } while (0)

#define RD_A(fm, kk) (*(const bf16x8*)&cA[(wm * 64 + (fm) * 16 + ln) * 64 + (((kk) * 32 + lg * 8) ^ swz)])
#define RD_B(fn, kk) (*(const bf16x8*)&cB[(wn * 64 + (fn) * 16 + ln) * 64 + (((kk) * 32 + lg * 8) ^ swz)])

#define MFMA_Q(fmA, fmB, fnA, fnB, aA0, aA1, aB0, aB1, bA0, bA1, bB0, bB1)       \
  __builtin_amdgcn_s_setprio(1);                                                  \
  acc[fmA][fnA] = __builtin_amdgcn_mfma_f32_16x16x32_bf16(aA0, bA0, acc[fmA][fnA], 0, 0, 0); \
  acc[fmA][fnA] = __builtin_amdgcn_mfma_f32_16x16x32_bf16(aA1, bA1, acc[fmA][fnA], 0, 0, 0); \
  acc[fmA][fnB] = __builtin_amdgcn_mfma_f32_16x16x32_bf16(aA0, bB0, acc[fmA][fnB], 0, 0, 0); \
  acc[fmA][fnB] = __builtin_amdgcn_mfma_f32_16x16x32_bf16(aA1, bB1, acc[fmA][fnB], 0, 0, 0); \
  acc[fmB][fnA] = __builtin_amdgcn_mfma_f32_16x16x32_bf16(aB0, bA0, acc[fmB][fnA], 0, 0, 0); \
  acc[fmB][fnA] = __builtin_amdgcn_mfma_f32_16x16x32_bf16(aB1, bA1, acc[fmB][fnA], 0, 0, 0); \
  acc[fmB][fnB] = __builtin_amdgcn_mfma_f32_16x16x32_bf16(aB0, bB0, acc[fmB][fnB], 0, 0, 0); \
  acc[fmB][fnB] = __builtin_amdgcn_mfma_f32_16x16x32_bf16(aB1, bB1, acc[fmB][fnB], 0, 0, 0); \
  __builtin_amdgcn_s_setprio(0);

#define GEMM_PIPELINE(Aptr, Bptr)                                                \
  const int tid = threadIdx.x;                                                   \
  const int lane = tid & 63, w = tid >> 6;                                       \
  const int wm = w >> 2, wn = w & 3;                                             \
  const int ln = lane & 15, lg = lane >> 4;                                      \
  const int lrow = lane >> 3;                                                    \
  const int kswz = (((lane & 7) ^ ((lane >> 3) & 7)) * 8);                       \
  const int swz = (ln & 7) << 3;                                                 \
  f32x4 acc[4][4];                                                               \
  _Pragma("unroll") for (int m = 0; m < 4; ++m)                                  \
    _Pragma("unroll") for (int n = 0; n < 4; ++n)                                \
      acc[m][n] = (f32x4){0.f, 0.f, 0.f, 0.f};                                   \
  stageA2(Aptr, m0, 0, LDSA(0), w, lrow, kswz);                                  \
  stageB1(Bptr, n0, 0, LDSB(0), 0, w, lrow, kswz);                               \
  stageB1(Bptr, n0, 0, LDSB(0), 1, w, lrow, kswz);                               \
  stageB1(Bptr, n0, 0, LDSB(0), 2, w, lrow, kswz);                               \
  stageB1(Bptr, n0, 0, LDSB(0), 3, w, lrow, kswz);                               \
  stageA2(Aptr, m0, 1, LDSA(1), w, lrow, kswz);                                  \
  stageB1(Bptr, n0, 1, LDSB(1), 0, w, lrow, kswz);                               \
  stageB1(Bptr, n0, 1, LDSB(1), 1, w, lrow, kswz);                               \
  stageB1(Bptr, n0, 1, LDSB(1), 2, w, lrow, kswz);                               \
  stageB1(Bptr, n0, 1, LDSB(1), 3, w, lrow, kswz);                               \
  asm volatile("s_waitcnt vmcnt(6)" ::: "memory");                               \
  __builtin_amdgcn_s_barrier();                                                  \
  int cur = 0;                                                                   \
  _Pragma("unroll 1") for (int t = 0; t < 16; ++t) {                             \
    const unsigned short* cA = LDSA(cur);                                        \
    const unsigned short* cB = LDSB(cur);                                        \
    int sb = cur + 2; if (sb >= 3) sb -= 3;                                      \
    unsigned short* nA = LDSA(sb);                                               \
    unsigned short* nB = LDSB(sb);                                               \
    const bool st = (t <= 13);                                                   \
    /* P0: read af01,bf01; stage A(t+2) */                                       \
    bf16x8 a0_0 = RD_A(0, 0), a0_1 = RD_A(0, 1);                                 \
    bf16x8 a1_0 = RD_A(1, 0), a1_1 = RD_A(1, 1);                                 \
    bf16x8 b0_0 = RD_B(0, 0), b0_1 = RD_B(0, 1);                                 \
    bf16x8 b1_0 = RD_B(1, 0), b1_1 = RD_B(1, 1);                                 \
    if (st) stageA2(Aptr, m0, t + 2, nA, w, lrow, kswz);                         \
    BARF();                                                                      \
    MFMA_Q(0, 1, 0, 1, a0_0, a0_1, a1_0, a1_1, b0_0, b0_1, b1_0, b1_1)           \
    BARF();                                                                      \
    /* P1: read bf23; stage B0,B1(t+2) */                                        \
    bf16x8 b2_0 = RD_B(2, 0), b2_1 = RD_B(2, 1);                                 \
    bf16x8 b3_0 = RD_B(3, 0), b3_1 = RD_B(3, 1);                                 \
    if (st) { stageB1(Bptr, n0, t + 2, nB, 0, w, lrow, kswz);                    \
              stageB1(Bptr, n0, t + 2, nB, 1, w, lrow, kswz); }                  \
    BARF();                                                                      \
    MFMA_Q(0, 1, 2, 3, a0_0, a0_1, a1_0, a1_1, b2_0, b2_1, b3_0, b3_1)           \
    BARF();                                                                      \
    /* P2: read af23; stage B2(t+2) */                                           \
    bf16x8 a2_0 = RD_A(2, 0), a2_1 = RD_A(2, 1);                                 \
    bf16x8 a3_0 = RD_A(3, 0), a3_1 = RD_A(3, 1);                                 \
    if (st) stageB1(Bptr, n0, t + 2, nB, 2, w, lrow, kswz);                      \
    BARF();                                                                      \
    MFMA_Q(2, 3, 2, 3, a2_0, a2_1, a3_0, a3_1, b2_0, b2_1, b3_0, b3_1)           \
    BARF();                                                                      \
    /* P3: stage B3(t+2); counted vmcnt validates tile t+1 */                    \
    if (st) stageB1(Bptr, n0, t + 2, nB, 3, w, lrow, kswz);                      \
    if (t < 14) { asm volatile("s_waitcnt vmcnt(6)" ::: "memory"); }             \
    else if (t == 14) { asm volatile("s_waitcnt vmcnt(0)" ::: "memory"); }       \
    BARF();                                                                      \
    MFMA_Q(2, 3, 0, 1, a2_0, a2_1, a3_0, a3_1, b0_0, b0_1, b1_0, b1_1)           \
    BARF();                                                                      \
    cur = cur + 1; if (cur == 3) cur = 0;                                        \
  }

// ---------------------------------------------------------------------------
// Fused QKV projection: A=HSB [8192,1024], W=WQKVB [1536,1024].
// by 0-1 -> QK f32 [8192,512]; by 2-5 -> V transposed to VTg[bh][v][t].
// Grid 384 = 64 bx * 6 by, bijective XCD swizzle, N-fastest within XCD.
// ---------------------------------------------------------------------------
__global__ __launch_bounds__(512) void proj_gemm(const unsigned short* __restrict__ A,
                                                 const unsigned short* __restrict__ Wb,
                                                 float* __restrict__ QK,
                                                 unsigned short* __restrict__ VTg) {
  __shared__ unsigned short lds[73728];
  const int bid = blockIdx.x;
  const int logical = (bid & 7) * 48 + (bid >> 3);  // 384 % 8 == 0
  const int bx = logical / 6, by = logical % 6;
  const int m0 = bx * 128, n0 = by * 256;

  GEMM_PIPELINE(A, Wb)

  if (by < 2) {
#pragma unroll
    for (int fm = 0; fm < 4; ++fm)
#pragma unroll
      for (int fn = 0; fn < 4; ++fn) {
        int col = n0 + wn * 64 + fn * 16 + ln;
        int row0 = m0 + wm * 64 + fm * 16 + lg * 4;
#pragma unroll
        for (int j = 0; j < 4; ++j)
          QK[(size_t)(row0 + j) * 512 + col] = acc[fm][fn][j];
      }
  } else {
    // stage transposed tile in LDS, then coalesced 16B stores along t
    unsigned short (*ct)[136] = (unsigned short(*)[136])lds;
#pragma unroll
    for (int fm = 0; fm < 4; ++fm)
#pragma unroll
      for (int fn = 0; fn < 4; ++fn) {
        int cl = wn * 64 + fn * 16 + ln;        // local v col 0..255
        int r0 = wm * 64 + fm * 16 + lg * 4;    // local t row 0..127
        us4 p;
#pragma unroll
        for (int j = 0; j < 4; ++j) p[j] = f2b(acc[fm][fn][j]);
        *(us4*)&ct[cl][r0] = p;
      }
    BARF();
    const int vbase = n0 - 512;
    const int b = m0 >> 11, t0 = m0 & 2047;
#pragma unroll
    for (int it = 0; it < 8; ++it) {
      int sid = it * 512 + tid, vl = sid >> 4, tc = sid & 15;
      int vg = vbase + vl, h = vg >> 6, vd = vg & 63;
      us8 val = *(const us8*)&ct[vl][tc * 8];
      *(us8*)&VTg[(((size_t)(b * 16 + h) * 64 + vd) << 11) + t0 + tc * 8] = val;
    }
  }
}

// ---------------------------------------------------------------------------
// Output GEMM: C[8192,1024] f32. Grid 256 = 64 bx * 4 by, XCD-swizzled.
// ---------------------------------------------------------------------------
__global__ __launch_bounds__(512) void out_gemm(const unsigned short* __restrict__ A,
                                                const unsigned short* __restrict__ W,
                                                float* __restrict__ C) {
  __shared__ unsigned short lds[73728];
  const int bid = blockIdx.x;
  const int logical = (bid & 7) * 32 + (bid >> 3);  // 256 % 8 == 0
  const int bx = logical >> 2, by = logical & 3;
  const int m0 = bx * 128, n0 = by * 256;

  GEMM_PIPELINE(A, W)

#pragma unroll
  for (int fm = 0; fm < 4; ++fm)
#pragma unroll
    for (int fn = 0; fn < 4; ++fn) {
      int col = n0 + wn * 64 + fn * 16 + ln;
      int row0 = m0 + wm * 64 + fm * 16 + lg * 4;
#pragma unroll
      for (int j = 0; j < 4; ++j)
        C[(size_t)(row0 + j) * 1024 + col] = acc[fm][fn][j];
    }
}

// ---------------------------------------------------------------------------
__device__ __forceinline__ void ln16(const float* __restrict__ src,
                                     const float* __restrict__ gamma,
                                     const float* __restrict__ beta,
                                     float* dst) {
  float x[16];
#pragma unroll
  for (int q = 0; q < 4; ++q) {
    float4 v = *(const float4*)(src + q * 4);
    x[q * 4 + 0] = v.x; x[q * 4 + 1] = v.y;
    x[q * 4 + 2] = v.z; x[q * 4 + 3] = v.w;
  }
  float mu = 0.f;
#pragma unroll
  for (int f = 0; f < 16; ++f) mu += x[f];
  mu *= 0.0625f;
  float var = 0.f;
#pragma unroll
  for (int f = 0; f < 16; ++f) { float d = x[f] - mu; var += d * d; }
  var *= 0.0625f;
  const float rs = rsqrtf(var + 1e-5f);
#pragma unroll
  for (int f = 0; f < 16; ++f) dst[f] = (x[f] - mu) * rs * gamma[f] + beta[f];
}

// ---------------------------------------------------------------------------
// Phase 1 (MFMA): S_raw_T[n][r] = sum_s kf[s][r] * V[s][n];  Mk gram (f32).
// ---------------------------------------------------------------------------
__global__ __launch_bounds__(256) void k_states(const float* __restrict__ QK,
                                                const unsigned short* __restrict__ VTg,
                                                const float* __restrict__ gamma,
                                                const float* __restrict__ beta,
                                                unsigned short* __restrict__ Sraw,
                                                float* __restrict__ Mk) {
  const int c = blockIdx.x, bh = blockIdx.y;
  const int b = bh >> 4, h = bh & 15;
  __shared__ float XKT[16][140];
  __shared__ unsigned short VT[64][152];
  const int tid = threadIdx.x;
  const int lane = tid & 63, wid = tid >> 6;
  const int ln = lane & 15, lg = lane >> 4;

  if (tid < 128) {
    float xr[16];
    ln16(QK + (size_t)(b * T_SEQ + c * CH + tid) * 512 + 256 + h * FDIM, gamma, beta, xr);
#pragma unroll
    for (int f = 0; f < 16; ++f) XKT[f][tid] = xr[f];
  }
#pragma unroll
  for (int it = 0; it < 4; ++it) {
    int flat = tid + it * 256; int v = flat >> 4, sb = flat & 15;
    *(us8*)&VT[v][sb * 8] = *(const us8*)&VTg[((size_t)bh * 64 + v) * T_SEQ + c * CH + sb * 8];
  }
  __syncthreads();

  {
    int i = tid >> 4, j = tid & 15;
    float m = 0.f;
    for (int cc = 0; cc < CH; ++cc) m += XKT[i][cc] * XKT[j][cc];
    Mk[((size_t)bh * NCHUNK + c) * 256 + tid] = m;
  }

  f32x4 acc[4][4];
#pragma unroll
  for (int m = 0; m < 4; ++m)
#pragma unroll
    for (int n = 0; n < 4; ++n) acc[m][n] = (f32x4){0.f, 0.f, 0.f, 0.f};

#pragma unroll
  for (int kt = 0; kt < 4; ++kt) {
    const int s0 = kt * 32 + lg * 8;
    bf16x8 bfr[4];
#pragma unroll
    for (int nt = 0; nt < 4; ++nt) bfr[nt] = *(const bf16x8*)&VT[nt * 16 + ln][s0];
#pragma unroll
    for (int mi = 0; mi < 4; ++mi) {
      const int iidx = wid * 4 + mi;
      float4 xi0 = *(const float4*)&XKT[iidx][s0];
      float4 xi1 = *(const float4*)&XKT[iidx][s0 + 4];
      float4 xj0 = *(const float4*)&XKT[ln][s0];
      float4 xj1 = *(const float4*)&XKT[ln][s0 + 4];
      bf16x8 afr;
      afr[0] = (short)f2b(xi0.x * xj0.x); afr[1] = (short)f2b(xi0.y * xj0.y);
      afr[2] = (short)f2b(xi0.z * xj0.z); afr[3] = (short)f2b(xi0.w * xj0.w);
      afr[4] = (short)f2b(xi1.x * xj1.x); afr[5] = (short)f2b(xi1.y * xj1.y);
      afr[6] = (short)f2b(xi1.z * xj1.z); afr[7] = (short)f2b(xi1.w * xj1.w);
#pragma unroll
      for (int nt = 0; nt < 4; ++nt)
        acc[mi][nt] = __builtin_amdgcn_mfma_f32_16x16x32_bf16(afr, bfr[nt], acc[mi][nt], 0, 0, 0);
    }
  }

  unsigned short* Sp = Sraw + ((size_t)bh * NCHUNK + c) * (64 * 256);
#pragma unroll
  for (int mi = 0; mi < 4; ++mi) {
    int r0 = (wid * 4 + mi) * 16 + lg * 4;
#pragma unroll
    for (int nt = 0; nt < 4; ++nt) {
      int n = nt * 16 + ln;
      us4 pk;
#pragma unroll
      for (int j = 0; j < 4; ++j) pk[j] = f2b(acc[mi][nt][j]);
      *(us4*)&Sp[(size_t)n * 256 + r0] = pk;
    }
  }
}

// ---------------------------------------------------------------------------
// Phase 2 merged: blockIdx.x<8 -> S prefix; ==8 -> Mk prefix.
// ---------------------------------------------------------------------------
__global__ __launch_bounds__(256) void k_prefix(const unsigned short* __restrict__ Sraw,
                                                unsigned short* __restrict__ Spre,
                                                float* __restrict__ Mk) {
  const int bh = blockIdx.y;
  if (blockIdx.x < 8) {
    const int e8 = blockIdx.x * 256 + threadIdx.x;
    size_t base = (size_t)bh * NCHUNK * 16384 + (size_t)e8 * 8;
    float run[8] = {0.f, 0.f, 0.f, 0.f, 0.f, 0.f, 0.f, 0.f};
    for (int cc = 0; cc < NCHUNK; ++cc) {
      us8 v = *(const us8*)&Sraw[base + (size_t)cc * 16384];
      us8 w;
#pragma unroll
      for (int q = 0; q < 8; ++q) w[q] = f2b(run[q]);
      *(us8*)&Spre[base + (size_t)cc * 16384] = w;
#pragma unroll
      for (int q = 0; q < 8; ++q) run[q] += b2f(v[q]);
    }
  } else {
    const int e = threadIdx.x;
    size_t base = (size_t)bh * NCHUNK * 256 + e;
    float run = 0.f;
    for (int c = 0; c < NCHUNK; ++c) {
      float v = Mk[base + (size_t)c * 256];
      Mk[base + (size_t)c * 256] = run;
      run += v;
    }
  }
}

// ---------------------------------------------------------------------------
// Phase 3 (MFMA): att = (XQ XK^T)^2/16 masked; o = att@V + qf@P; z in f32.
// ---------------------------------------------------------------------------
__global__ __launch_bounds__(256) void k_attn_out(const float* __restrict__ QK,
                                                  const unsigned short* __restrict__ VTg,
                                                  const float* __restrict__ gamma,
                                                  const float* __restrict__ beta,
                                                  const unsigned short* __restrict__ Spre,
                                                  const float* __restrict__ Mkp,
                                                  unsigned short* __restrict__ OAB) {
  const int c = blockIdx.x, bh = blockIdx.y;
  const int b = bh >> 4, h = bh & 15;
  __shared__ unsigned short XQb[128][40];
  __shared__ unsigned short XKb[128][40];
  __shared__ unsigned short attb[128 * 128];
  __shared__ unsigned short VT[64][152];
  __shared__ float mksh[256];
  const int tid = threadIdx.x;
  const int lane = tid & 63, wid = tid >> 6;
  const int ln = lane & 15, lg = lane >> 4;

  {
    int r = tid & 127;
    const float* src = QK + (size_t)(b * T_SEQ + c * CH + r) * 512 + (tid < 128 ? 0 : 256) + h * FDIM;
    unsigned short* dst = (tid < 128) ? &XQb[r][0] : &XKb[r][0];
    float xr[16];
    ln16(src, gamma, beta, xr);
    us8 lo, hi, z8;
#pragma unroll
    for (int q = 0; q < 8; ++q) { lo[q] = f2b(xr[q]); hi[q] = f2b(xr[8 + q]); z8[q] = 0; }
    *(us8*)&dst[0] = lo; *(us8*)&dst[8] = hi;
    *(us8*)&dst[16] = z8; *(us8*)&dst[24] = z8;
  }
#pragma unroll
  for (int it = 0; it < 4; ++it) {
    int flat = tid + it * 256; int v = flat >> 4, sb = flat & 15;
    *(us8*)&VT[v][sb * 8] = *(const us8*)&VTg[((size_t)bh * 64 + v) * T_SEQ + c * CH + sb * 8];
  }
  mksh[tid] = Mkp[((size_t)bh * NCHUNK + c) * 256 + tid];
  __syncthreads();

  const int tb = wid * 32;
  const f32x4 zero4 = {0.f, 0.f, 0.f, 0.f};

  bf16x8 aq0 = *(const bf16x8*)&XQb[tb + ln][lg * 8];
  bf16x8 aq1 = *(const bf16x8*)&XQb[tb + 16 + ln][lg * 8];
  float zin[2][4];
#pragma unroll
  for (int mt = 0; mt < 2; ++mt)
#pragma unroll
    for (int j = 0; j < 4; ++j) zin[mt][j] = 0.f;

#pragma unroll
  for (int nt = 0; nt < 8; ++nt) {
    bf16x8 bk = *(const bf16x8*)&XKb[nt * 16 + ln][lg * 8];
    f32x4 c0 = __builtin_amdgcn_mfma_f32_16x16x32_bf16(aq0, bk, zero4, 0, 0, 0);
    f32x4 c1 = __builtin_amdgcn_mfma_f32_16x16x32_bf16(aq1, bk, zero4, 0, 0, 0);
    int s = nt * 16 + ln;
#pragma unroll
    for (int j = 0; j < 4; ++j) {
      int t0 = tb + lg * 4 + j;
      float d0 = c0[j];
      float a0 = (s <= t0) ? d0 * d0 * 0.0625f : 0.f;
      zin[0][j] += a0;
      attb[t0 * 128 + (s ^ ((t0 & 7) << 3))] = f2b(a0);
      int t1 = t0 + 16;
      float d1 = c1[j];
      float a1 = (s <= t1) ? d1 * d1 * 0.0625f : 0.f;
      zin[1][j] += a1;
      attb[t1 * 128 + (s ^ ((t1 & 7) << 3))] = f2b(a1);
    }
  }
#pragma unroll
  for (int mt = 0; mt < 2; ++mt)
#pragma unroll
    for (int j = 0; j < 4; ++j) {
      float zz = zin[mt][j];
      zz += __shfl_xor(zz, 1, 64);
      zz += __shfl_xor(zz, 2, 64);
      zz += __shfl_xor(zz, 4, 64);
      zz += __shfl_xor(zz, 8, 64);
      zin[mt][j] = zz;
    }

  f32x4 o[2][4];
#pragma unroll
  for (int mt = 0; mt < 2; ++mt)
#pragma unroll
    for (int nt = 0; nt < 4; ++nt) o[mt][nt] = zero4;

#pragma unroll
  for (int kt = 0; kt < 4; ++kt) {
    int s0 = kt * 32 + lg * 8;
    bf16x8 a0 = *(const bf16x8*)&attb[(tb + ln) * 128 + (s0 ^ ((ln & 7) << 3))];
    bf16x8 a1 = *(const bf16x8*)&attb[(tb + 16 + ln) * 128 + (s0 ^ ((ln & 7) << 3))];
#pragma unroll
    for (int nt = 0; nt < 4; ++nt) {
      bf16x8 bv = *(const bf16x8*)&VT[nt * 16 + ln][s0];
      o[0][nt] = __builtin_amdgcn_mfma_f32_16x16x32_bf16(a0, bv, o[0][nt], 0, 0, 0);
      o[1][nt] = __builtin_amdgcn_mfma_f32_16x16x32_bf16(a1, bv, o[1][nt], 0, 0, 0);
    }
  }

  const unsigned short* Sp = Spre + ((size_t)bh * NCHUNK + c) * (64 * 256);
  bf16x8 xlo0 = *(const bf16x8*)&XQb[tb + ln][0];
  bf16x8 xhi0 = *(const bf16x8*)&XQb[tb + ln][8];
  bf16x8 xlo1 = *(const bf16x8*)&XQb[tb + 16 + ln][0];
  bf16x8 xhi1 = *(const bf16x8*)&XQb[tb + 16 + ln][8];
#pragma unroll
  for (int kt = 0; kt < 8; ++kt) {
    int i = kt * 2 + (lg >> 1);
    float xqi0 = b2f(XQb[tb + ln][i]) * 0.0625f;
    float xqi1 = b2f(XQb[tb + 16 + ln][i]) * 0.0625f;
    bf16x8 sel0 = (lg & 1) ? xhi0 : xlo0;
    bf16x8 sel1 = (lg & 1) ? xhi1 : xlo1;
    bf16x8 qa0, qa1;
#pragma unroll
    for (int jj = 0; jj < 8; ++jj) {
      qa0[jj] = (short)f2b(xqi0 * b2f((unsigned short)sel0[jj]));
      qa1[jj] = (short)f2b(xqi1 * b2f((unsigned short)sel1[jj]));
    }
    int r0 = kt * 32 + lg * 8;
#pragma unroll
    for (int nt = 0; nt < 4; ++nt) {
      bf16x8 bp = *(const bf16x8*)&Sp[(size_t)(nt * 16 + ln) * 256 + r0];
      o[0][nt] = __builtin_amdgcn_mfma_f32_16x16x32_bf16(qa0, bp, o[0][nt], 0, 0, 0);
      o[1][nt] = __builtin_amdgcn_mfma_f32_16x16x32_bf16(qa1, bp, o[1][nt], 0, 0, 0);
    }
  }

  float zi2[2][4];
#pragma unroll
  for (int mt = 0; mt < 2; ++mt)
#pragma unroll
    for (int j = 0; j < 4; ++j) {
      int t = tb + mt * 16 + lg * 4 + j;
      float xqi = b2f(XQb[t][ln]);
      float p = 0.f;
#pragma unroll
      for (int jm = 0; jm < 16; ++jm) p += b2f(XQb[t][jm]) * mksh[jm * 16 + ln];
      p *= xqi;
      p += __shfl_xor(p, 1, 64);
      p += __shfl_xor(p, 2, 64);
      p += __shfl_xor(p, 4, 64);
      p += __shfl_xor(p, 8, 64);
      zi2[mt][j] = p * 0.0625f;
    }

  unsigned short* ob = OAB + ((size_t)(b * T_SEQ + c * CH)) * 1024 + h * 64;
#pragma unroll
  for (int mt = 0; mt < 2; ++mt)
#pragma unroll
    for (int j = 0; j < 4; ++j) {
      int t = tb + mt * 16 + lg * 4 + j;
      float inv = 1.0f / (zin[mt][j] + zi2[mt][j] + 1e-10f);
#pragma unroll
      for (int nt = 0; nt < 4; ++nt)
        ob[(size_t)t * 1024 + nt * 16 + ln] = f2b(o[mt][nt][j] * inv);
    }
}

// ---------------------------------------------------------------------------
extern "C" void kernel_launch(void* const* d_in, const int* in_sizes, int n_in,
                              void* d_out, int out_size, void* d_ws, size_t ws_size,
                              hipStream_t stream) {
  const float* hs    = (const float*)d_in[0];
  const float* Wq    = (const float*)d_in[1];
  const float* Wk    = (const float*)d_in[2];
  const float* Wv    = (const float*)d_in[3];
  const float* Wo    = (const float*)d_in[4];
  const float* gamma = (const float*)d_in[5];
  const float* beta  = (const float*)d_in[6];
  float* out = (float*)d_out;
  float* ws  = (float*)d_ws;

  float* QK = ws + QK_OFF;
  unsigned short* VTg   = (unsigned short*)(ws + VT_OFF);
  unsigned short* Sraw  = (unsigned short*)(ws + SRAW_OFF);
  unsigned short* Spre  = (unsigned short*)(ws + SPRE_OFF);
  float* Mk = ws + MK_OFF;
  unsigned short* OAB   = (unsigned short*)(ws + OAB_OFF);
  unsigned short* WQKVB = (unsigned short*)(ws + WQKV_OFF);
  unsigned short* WOB   = (unsigned short*)(ws + WO_OFF);
  unsigned short* HSB   = (unsigned short*)(ws + HSB_OFF);

  dim3 blk(256);
  conv_all<<<5376, blk, 0, stream>>>(hs, Wq, Wk, Wv, Wo, HSB, WQKVB, WOB);
  proj_gemm<<<384, dim3(512), 0, stream>>>(HSB, WQKVB, QK, VTg);
  k_states<<<dim3(NCHUNK, NBH), blk, 0, stream>>>(QK, VTg, gamma, beta, Sraw, Mk);
  k_prefix<<<dim3(9, NBH), blk, 0, stream>>>(Sraw, Spre, Mk);
  k_attn_out<<<dim3(NCHUNK, NBH), blk, 0, stream>>>(QK, VTg, gamma, beta, Spre, Mk, OAB);
  out_gemm<<<256, dim3(512), 0, stream>>>(OAB, WOB, out);
}

// Round 8
// 127.413 us; speedup vs baseline: 1.3620x; 1.0797x over previous
//
#include <hip/hip_runtime.h>

#define T_SEQ 2048
#define BATCH 4
#define NH 16
#define FDIM 16
#define HDIM 64
#define HIDDEN 1024
#define TOK (BATCH * T_SEQ)      // 8192
#define CH 128
#define NCHUNK (T_SEQ / CH)      // 16
#define NBH (BATCH * NH)         // 64

// workspace offsets (float32 units)
#define QK_OFF   0u              // f32 [TOK, 512]  (Q cols 0..255, K cols 256..511)
#define VT_OFF   4194304u        // bf16 [NBH][64 v][2048 t]
#define SRAW_OFF 8388608u        // bf16 [NBH][NCHUNK][64 n][256 r]
#define SPRE_OFF 16777216u       // bf16 same layout (exclusive prefix)
#define MK_OFF   25165824u       // f32 [NBH][NCHUNK][256]
#define OAB_OFF  25427968u       // bf16 [TOK,1024]
#define WQKV_OFF 29622272u       // bf16 [1536,1024] (Wq 0-255, Wk 256-511, Wv 512-1535)
#define WO_OFF   30408704u       // bf16 [1024,1024]
#define HSB_OFF  30932992u       // bf16 [TOK,1024]

typedef float f32x4 __attribute__((ext_vector_type(4)));
typedef short bf16x8 __attribute__((ext_vector_type(8)));
typedef unsigned short us8 __attribute__((ext_vector_type(8)));
typedef unsigned short us4 __attribute__((ext_vector_type(4)));
typedef unsigned int u32;

__device__ __forceinline__ unsigned short f2b(float f) {
  union { float f; unsigned u; } v; v.f = f;
  unsigned r = (v.u + 0x7FFFu + ((v.u >> 16) & 1u)) >> 16;
  return (unsigned short)r;
}
__device__ __forceinline__ float b2f(unsigned short h) {
  union { unsigned u; float f; } v; v.u = ((unsigned)h) << 16; return v.f;
}

__device__ __forceinline__ void gload_lds16(const void* g, void* l) {
  __builtin_amdgcn_global_load_lds(
      (const __attribute__((address_space(1))) u32*)g,
      (__attribute__((address_space(3))) u32*)l, 16, 0, 0);
}

// ---------------------------------------------------------------------------
// One convert kernel: hs -> HSB, Wq|Wk|Wv -> WQKVB, Wo -> WOB. 8 elts/thread.
// ---------------------------------------------------------------------------
__global__ __launch_bounds__(256) void conv_all(const float* __restrict__ hs,
                                                const float* __restrict__ Wq,
                                                const float* __restrict__ Wk,
                                                const float* __restrict__ Wv,
                                                const float* __restrict__ Wo,
                                                unsigned short* __restrict__ HSB,
                                                unsigned short* __restrict__ WQKVB,
                                                unsigned short* __restrict__ WOB) {
  int i = blockIdx.x * 256 + threadIdx.x;
  const float* src;
  unsigned short* dst;
  if (i < 1048576) {
    int f = i * 8; src = hs + f; dst = HSB + f;
  } else if (i < 1245184) {
    int f = (i - 1048576) * 8;
    if (f < 262144)      src = Wq + f;
    else if (f < 524288) src = Wk + (f - 262144);
    else                 src = Wv + (f - 524288);
    dst = WQKVB + f;
  } else {
    int f = (i - 1245184) * 8;
    src = Wo + f; dst = WOB + f;
  }
  float4 v0 = *(const float4*)src, v1 = *(const float4*)(src + 4);
  us8 o;
  o[0] = f2b(v0.x); o[1] = f2b(v0.y); o[2] = f2b(v0.z); o[3] = f2b(v0.w);
  o[4] = f2b(v1.x); o[5] = f2b(v1.y); o[6] = f2b(v1.z); o[7] = f2b(v1.w);
  *(us8*)dst = o;
}

// ---------------------------------------------------------------------------
// GEMM core: BM=BN=128, BK=64, 256 thr (4 waves 2x2, per-wave 64x64).
// 2-deep LDS (64 KiB -> 2 blocks/CU, m114 cross-block overlap). Counted
// vmcnt(8): stage t+2 into the buffer consumed this iter (safe: lgkmcnt(0)+
// barrier precede), validate t+1 after MFMA -- never drains until epilogue.
// T2 swizzle both-sides (pre-swizzled global k-offset + XOR on read). T5.
// ---------------------------------------------------------------------------
#define LDSA(p) (lds + (p) * 8192)
#define LDSB(p) (lds + 16384 + (p) * 8192)

__device__ __forceinline__ void stage8(const unsigned short* __restrict__ A,
                                       const unsigned short* __restrict__ B,
                                       int m0, int n0, int kt,
                                       unsigned short* lA, unsigned short* lB,
                                       int w, int lrow, int kswz) {
  const int kc = kt * 64 + kswz;
#pragma unroll
  for (int i = 0; i < 4; ++i) {
    int r = w * 32 + i * 8;
    gload_lds16(&A[(size_t)(m0 + r + lrow) * HIDDEN + kc], &lA[r * 64]);
  }
#pragma unroll
  for (int i = 0; i < 4; ++i) {
    int r = w * 32 + i * 8;
    gload_lds16(&B[(size_t)(n0 + r + lrow) * HIDDEN + kc], &lB[r * 64]);
  }
}

#define RD_A(fm, kk) (*(const bf16x8*)&cA[(wm * 64 + (fm) * 16 + ln) * 64 + (((kk) * 32 + lg * 8) ^ swz)])
#define RD_B(fn, kk) (*(const bf16x8*)&cB[(wn * 64 + (fn) * 16 + ln) * 64 + (((kk) * 32 + lg * 8) ^ swz)])

#define GEMM_PIPELINE(Aptr, Bptr)                                              \
  const int tid = threadIdx.x;                                                 \
  const int lane = tid & 63, w = tid >> 6;                                     \
  const int wm = w >> 1, wn = w & 1;                                           \
  const int ln = lane & 15, lg = lane >> 4;                                    \
  const int lrow = lane >> 3;                                                  \
  const int kswz = (((lane & 7) ^ ((lane >> 3) & 7)) * 8);                     \
  const int swz = (ln & 7) << 3;                                               \
  f32x4 acc[4][4];                                                             \
  _Pragma("unroll") for (int m = 0; m < 4; ++m)                                \
    _Pragma("unroll") for (int n = 0; n < 4; ++n)                              \
      acc[m][n] = (f32x4){0.f, 0.f, 0.f, 0.f};                                 \
  stage8(Aptr, Bptr, m0, n0, 0, LDSA(0), LDSB(0), w, lrow, kswz);              \
  stage8(Aptr, Bptr, m0, n0, 1, LDSA(1), LDSB(1), w, lrow, kswz);              \
  asm volatile("s_waitcnt vmcnt(8)" ::: "memory");                             \
  __builtin_amdgcn_s_barrier();                                                \
  _Pragma("unroll 1") for (int t = 0; t < 16; ++t) {                           \
    const unsigned short* cA = LDSA(t & 1);                                    \
    const unsigned short* cB = LDSB(t & 1);                                    \
    bf16x8 af[4][2], bfr[4][2];                                                \
    _Pragma("unroll") for (int f = 0; f < 4; ++f) {                            \
      af[f][0] = RD_A(f, 0); af[f][1] = RD_A(f, 1);                            \
      bfr[f][0] = RD_B(f, 0); bfr[f][1] = RD_B(f, 1);                          \
    }                                                                          \
    asm volatile("s_waitcnt lgkmcnt(0)" ::: "memory");                         \
    __builtin_amdgcn_sched_barrier(0);                                         \
    __builtin_amdgcn_s_barrier();                                              \
    if (t <= 13)                                                               \
      stage8(Aptr, Bptr, m0, n0, t + 2, LDSA(t & 1), LDSB(t & 1), w, lrow, kswz); \
    __builtin_amdgcn_s_setprio(1);                                             \
    _Pragma("unroll") for (int kk = 0; kk < 2; ++kk)                           \
      _Pragma("unroll") for (int fm = 0; fm < 4; ++fm)                         \
        _Pragma("unroll") for (int fn = 0; fn < 4; ++fn)                       \
          acc[fm][fn] = __builtin_amdgcn_mfma_f32_16x16x32_bf16(               \
              af[fm][kk], bfr[fn][kk], acc[fm][fn], 0, 0, 0);                  \
    __builtin_amdgcn_s_setprio(0);                                             \
    if (t <= 13) { asm volatile("s_waitcnt vmcnt(8)" ::: "memory"); }          \
    else if (t == 14) { asm volatile("s_waitcnt vmcnt(0)" ::: "memory"); }     \
    __builtin_amdgcn_s_barrier();                                              \
  }

// ---------------------------------------------------------------------------
// Fused QKV projection: A=HSB [8192,1024], W=WQKVB [1536,1024].
// by 0-3 -> QK f32 [8192,512]; by 4-11 -> V transposed to VTg[bh][v][t].
// Grid 768 = 64 bx * 12 by, bijective XCD swizzle, N-fastest within XCD.
// ---------------------------------------------------------------------------
__global__ __launch_bounds__(256) void proj_gemm(const unsigned short* __restrict__ A,
                                                 const unsigned short* __restrict__ Wb,
                                                 float* __restrict__ QK,
                                                 unsigned short* __restrict__ VTg) {
  __shared__ unsigned short lds[32768];  // 64 KiB
  const int bid = blockIdx.x;
  const int logical = (bid & 7) * 96 + (bid >> 3);  // 768 % 8 == 0
  const int bx = logical / 12, by = logical % 12;
  const int m0 = bx * 128, n0 = by * 128;

  GEMM_PIPELINE(A, Wb)

  if (by < 4) {
    // QK path: f32 row-major [8192, 512]
#pragma unroll
    for (int fm = 0; fm < 4; ++fm)
#pragma unroll
      for (int fn = 0; fn < 4; ++fn) {
        int col = n0 + wn * 64 + fn * 16 + ln;
        int row0 = m0 + wm * 64 + fm * 16 + lg * 4;
#pragma unroll
        for (int j = 0; j < 4; ++j)
          QK[(size_t)(row0 + j) * 512 + col] = acc[fm][fn][j];
      }
  } else {
    // V path: stage transposed tile in LDS, then coalesced 16B stores along t
    unsigned short (*ct)[136] = (unsigned short(*)[136])lds;
#pragma unroll
    for (int fm = 0; fm < 4; ++fm)
#pragma unroll
      for (int fn = 0; fn < 4; ++fn) {
        int cl = wn * 64 + fn * 16 + ln;        // local v col 0..127
        int r0 = wm * 64 + fm * 16 + lg * 4;    // local t row 0..127
        us4 p;
#pragma unroll
        for (int j = 0; j < 4; ++j) p[j] = f2b(acc[fm][fn][j]);
        *(us4*)&ct[cl][r0] = p;
      }
    __builtin_amdgcn_s_barrier();
    asm volatile("" ::: "memory");
    const int vbase = n0 - 512;
    const int b = m0 >> 11, t0 = m0 & 2047;
#pragma unroll
    for (int it = 0; it < 8; ++it) {
      int sid = it * 256 + tid, vl = sid >> 4, tc = sid & 15;
      int vg = vbase + vl, h = vg >> 6, vd = vg & 63;
      us8 val = *(const us8*)&ct[vl][tc * 8];
      *(us8*)&VTg[(((size_t)(b * 16 + h) * 64 + vd) << 11) + t0 + tc * 8] = val;
    }
  }
}

// ---------------------------------------------------------------------------
// Output GEMM: C[8192,1024] f32. Grid 512 = 64 bx * 8 by, XCD-swizzled.
// ---------------------------------------------------------------------------
__global__ __launch_bounds__(256) void out_gemm(const unsigned short* __restrict__ A,
                                                const unsigned short* __restrict__ W,
                                                float* __restrict__ C) {
  __shared__ unsigned short lds[32768];  // 64 KiB
  const int bid = blockIdx.x;
  const int logical = (bid & 7) * 64 + (bid >> 3);  // 512 % 8 == 0
  const int bx = logical >> 3, by = logical & 7;
  const int m0 = bx * 128, n0 = by * 128;

  GEMM_PIPELINE(A, W)

#pragma unroll
  for (int fm = 0; fm < 4; ++fm)
#pragma unroll
    for (int fn = 0; fn < 4; ++fn) {
      int col = n0 + wn * 64 + fn * 16 + ln;
      int row0 = m0 + wm * 64 + fm * 16 + lg * 4;
#pragma unroll
      for (int j = 0; j < 4; ++j)
        C[(size_t)(row0 + j) * 1024 + col] = acc[fm][fn][j];
    }
}

// ---------------------------------------------------------------------------
__device__ __forceinline__ void ln16(const float* __restrict__ src,
                                     const float* __restrict__ gamma,
                                     const float* __restrict__ beta,
                                     float* dst) {
  float x[16];
#pragma unroll
  for (int q = 0; q < 4; ++q) {
    float4 v = *(const float4*)(src + q * 4);
    x[q * 4 + 0] = v.x; x[q * 4 + 1] = v.y;
    x[q * 4 + 2] = v.z; x[q * 4 + 3] = v.w;
  }
  float mu = 0.f;
#pragma unroll
  for (int f = 0; f < 16; ++f) mu += x[f];
  mu *= 0.0625f;
  float var = 0.f;
#pragma unroll
  for (int f = 0; f < 16; ++f) { float d = x[f] - mu; var += d * d; }
  var *= 0.0625f;
  const float rs = rsqrtf(var + 1e-5f);
#pragma unroll
  for (int f = 0; f < 16; ++f) dst[f] = (x[f] - mu) * rs * gamma[f] + beta[f];
}

// ---------------------------------------------------------------------------
// Phase 1 (MFMA): S_raw_T[n][r] = sum_s kf[s][r] * V[s][n];  Mk gram (f32).
// ---------------------------------------------------------------------------
__global__ __launch_bounds__(256) void k_states(const float* __restrict__ QK,
                                                const unsigned short* __restrict__ VTg,
                                                const float* __restrict__ gamma,
                                                const float* __restrict__ beta,
                                                unsigned short* __restrict__ Sraw,
                                                float* __restrict__ Mk) {
  const int c = blockIdx.x, bh = blockIdx.y;
  const int b = bh >> 4, h = bh & 15;
  __shared__ float XKT[16][140];
  __shared__ unsigned short VT[64][152];
  const int tid = threadIdx.x;
  const int lane = tid & 63, wid = tid >> 6;
  const int ln = lane & 15, lg = lane >> 4;

  if (tid < 128) {
    float xr[16];
    ln16(QK + (size_t)(b * T_SEQ + c * CH + tid) * 512 + 256 + h * FDIM, gamma, beta, xr);
#pragma unroll
    for (int f = 0; f < 16; ++f) XKT[f][tid] = xr[f];
  }
#pragma unroll
  for (int it = 0; it < 4; ++it) {
    int flat = tid + it * 256; int v = flat >> 4, sb = flat & 15;
    *(us8*)&VT[v][sb * 8] = *(const us8*)&VTg[((size_t)bh * 64 + v) * T_SEQ + c * CH + sb * 8];
  }
  __syncthreads();

  {
    int i = tid >> 4, j = tid & 15;
    float m = 0.f;
    for (int cc = 0; cc < CH; ++cc) m += XKT[i][cc] * XKT[j][cc];
    Mk[((size_t)bh * NCHUNK + c) * 256 + tid] = m;
  }

  f32x4 acc[4][4];
#pragma unroll
  for (int m = 0; m < 4; ++m)
#pragma unroll
    for (int n = 0; n < 4; ++n) acc[m][n] = (f32x4){0.f, 0.f, 0.f, 0.f};

#pragma unroll
  for (int kt = 0; kt < 4; ++kt) {
    const int s0 = kt * 32 + lg * 8;
    bf16x8 bfr[4];
#pragma unroll
    for (int nt = 0; nt < 4; ++nt) bfr[nt] = *(const bf16x8*)&VT[nt * 16 + ln][s0];
#pragma unroll
    for (int mi = 0; mi < 4; ++mi) {
      const int iidx = wid * 4 + mi;
      float4 xi0 = *(const float4*)&XKT[iidx][s0];
      float4 xi1 = *(const float4*)&XKT[iidx][s0 + 4];
      float4 xj0 = *(const float4*)&XKT[ln][s0];
      float4 xj1 = *(const float4*)&XKT[ln][s0 + 4];
      bf16x8 afr;
      afr[0] = (short)f2b(xi0.x * xj0.x); afr[1] = (short)f2b(xi0.y * xj0.y);
      afr[2] = (short)f2b(xi0.z * xj0.z); afr[3] = (short)f2b(xi0.w * xj0.w);
      afr[4] = (short)f2b(xi1.x * xj1.x); afr[5] = (short)f2b(xi1.y * xj1.y);
      afr[6] = (short)f2b(xi1.z * xj1.z); afr[7] = (short)f2b(xi1.w * xj1.w);
#pragma unroll
      for (int nt = 0; nt < 4; ++nt)
        acc[mi][nt] = __builtin_amdgcn_mfma_f32_16x16x32_bf16(afr, bfr[nt], acc[mi][nt], 0, 0, 0);
    }
  }

  unsigned short* Sp = Sraw + ((size_t)bh * NCHUNK + c) * (64 * 256);
#pragma unroll
  for (int mi = 0; mi < 4; ++mi) {
    int r0 = (wid * 4 + mi) * 16 + lg * 4;
#pragma unroll
    for (int nt = 0; nt < 4; ++nt) {
      int n = nt * 16 + ln;
      us4 pk;
#pragma unroll
      for (int j = 0; j < 4; ++j) pk[j] = f2b(acc[mi][nt][j]);
      *(us4*)&Sp[(size_t)n * 256 + r0] = pk;
    }
  }
}

// ---------------------------------------------------------------------------
// Phase 2 merged: blockIdx.x<8 -> S prefix; ==8 -> Mk prefix.
// ---------------------------------------------------------------------------
__global__ __launch_bounds__(256) void k_prefix(const unsigned short* __restrict__ Sraw,
                                                unsigned short* __restrict__ Spre,
                                                float* __restrict__ Mk) {
  const int bh = blockIdx.y;
  if (blockIdx.x < 8) {
    const int e8 = blockIdx.x * 256 + threadIdx.x;
    size_t base = (size_t)bh * NCHUNK * 16384 + (size_t)e8 * 8;
    float run[8] = {0.f, 0.f, 0.f, 0.f, 0.f, 0.f, 0.f, 0.f};
    for (int cc = 0; cc < NCHUNK; ++cc) {
      us8 v = *(const us8*)&Sraw[base + (size_t)cc * 16384];
      us8 w;
#pragma unroll
      for (int q = 0; q < 8; ++q) w[q] = f2b(run[q]);
      *(us8*)&Spre[base + (size_t)cc * 16384] = w;
#pragma unroll
      for (int q = 0; q < 8; ++q) run[q] += b2f(v[q]);
    }
  } else {
    const int e = threadIdx.x;
    size_t base = (size_t)bh * NCHUNK * 256 + e;
    float run = 0.f;
    for (int c = 0; c < NCHUNK; ++c) {
      float v = Mk[base + (size_t)c * 256];
      Mk[base + (size_t)c * 256] = run;
      run += v;
    }
  }
}

// ---------------------------------------------------------------------------
// Phase 3 (MFMA): att = (XQ XK^T)^2/16 masked; o = att@V + qf@P; z in f32.
// ---------------------------------------------------------------------------
__global__ __launch_bounds__(256) void k_attn_out(const float* __restrict__ QK,
                                                  const unsigned short* __restrict__ VTg,
                                                  const float* __restrict__ gamma,
                                                  const float* __restrict__ beta,
                                                  const unsigned short* __restrict__ Spre,
                                                  const float* __restrict__ Mkp,
                                                  unsigned short* __restrict__ OAB) {
  const int c = blockIdx.x, bh = blockIdx.y;
  const int b = bh >> 4, h = bh & 15;
  __shared__ unsigned short XQb[128][40];
  __shared__ unsigned short XKb[128][40];
  __shared__ unsigned short attb[128 * 128];
  __shared__ unsigned short VT[64][152];
  __shared__ float mksh[256];
  const int tid = threadIdx.x;
  const int lane = tid & 63, wid = tid >> 6;
  const int ln = lane & 15, lg = lane >> 4;

  {
    int r = tid & 127;
    const float* src = QK + (size_t)(b * T_SEQ + c * CH + r) * 512 + (tid < 128 ? 0 : 256) + h * FDIM;
    unsigned short* dst = (tid < 128) ? &XQb[r][0] : &XKb[r][0];
    float xr[16];
    ln16(src, gamma, beta, xr);
    us8 lo, hi, z8;
#pragma unroll
    for (int q = 0; q < 8; ++q) { lo[q] = f2b(xr[q]); hi[q] = f2b(xr[8 + q]); z8[q] = 0; }
    *(us8*)&dst[0] = lo; *(us8*)&dst[8] = hi;
    *(us8*)&dst[16] = z8; *(us8*)&dst[24] = z8;
  }
#pragma unroll
  for (int it = 0; it < 4; ++it) {
    int flat = tid + it * 256; int v = flat >> 4, sb = flat & 15;
    *(us8*)&VT[v][sb * 8] = *(const us8*)&VTg[((size_t)bh * 64 + v) * T_SEQ + c * CH + sb * 8];
  }
  mksh[tid] = Mkp[((size_t)bh * NCHUNK + c) * 256 + tid];
  __syncthreads();

  const int tb = wid * 32;
  const f32x4 zero4 = {0.f, 0.f, 0.f, 0.f};

  bf16x8 aq0 = *(const bf16x8*)&XQb[tb + ln][lg * 8];
  bf16x8 aq1 = *(const bf16x8*)&XQb[tb + 16 + ln][lg * 8];
  float zin[2][4];
#pragma unroll
  for (int mt = 0; mt < 2; ++mt)
#pragma unroll
    for (int j = 0; j < 4; ++j) zin[mt][j] = 0.f;

#pragma unroll
  for (int nt = 0; nt < 8; ++nt) {
    bf16x8 bk = *(const bf16x8*)&XKb[nt * 16 + ln][lg * 8];
    f32x4 c0 = __builtin_amdgcn_mfma_f32_16x16x32_bf16(aq0, bk, zero4, 0, 0, 0);
    f32x4 c1 = __builtin_amdgcn_mfma_f32_16x16x32_bf16(aq1, bk, zero4, 0, 0, 0);
    int s = nt * 16 + ln;
#pragma unroll
    for (int j = 0; j < 4; ++j) {
      int t0 = tb + lg * 4 + j;
      float d0 = c0[j];
      float a0 = (s <= t0) ? d0 * d0 * 0.0625f : 0.f;
      zin[0][j] += a0;
      attb[t0 * 128 + (s ^ ((t0 & 7) << 3))] = f2b(a0);
      int t1 = t0 + 16;
      float d1 = c1[j];
      float a1 = (s <= t1) ? d1 * d1 * 0.0625f : 0.f;
      zin[1][j] += a1;
      attb[t1 * 128 + (s ^ ((t1 & 7) << 3))] = f2b(a1);
    }
  }
#pragma unroll
  for (int mt = 0; mt < 2; ++mt)
#pragma unroll
    for (int j = 0; j < 4; ++j) {
      float zz = zin[mt][j];
      zz += __shfl_xor(zz, 1, 64);
      zz += __shfl_xor(zz, 2, 64);
      zz += __shfl_xor(zz, 4, 64);
      zz += __shfl_xor(zz, 8, 64);
      zin[mt][j] = zz;
    }

  f32x4 o[2][4];
#pragma unroll
  for (int mt = 0; mt < 2; ++mt)
#pragma unroll
    for (int nt = 0; nt < 4; ++nt) o[mt][nt] = zero4;

#pragma unroll
  for (int kt = 0; kt < 4; ++kt) {
    int s0 = kt * 32 + lg * 8;
    bf16x8 a0 = *(const bf16x8*)&attb[(tb + ln) * 128 + (s0 ^ ((ln & 7) << 3))];
    bf16x8 a1 = *(const bf16x8*)&attb[(tb + 16 + ln) * 128 + (s0 ^ ((ln & 7) << 3))];
#pragma unroll
    for (int nt = 0; nt < 4; ++nt) {
      bf16x8 bv = *(const bf16x8*)&VT[nt * 16 + ln][s0];
      o[0][nt] = __builtin_amdgcn_mfma_f32_16x16x32_bf16(a0, bv, o[0][nt], 0, 0, 0);
      o[1][nt] = __builtin_amdgcn_mfma_f32_16x16x32_bf16(a1, bv, o[1][nt], 0, 0, 0);
    }
  }

  const unsigned short* Sp = Spre + ((size_t)bh * NCHUNK + c) * (64 * 256);
  bf16x8 xlo0 = *(const bf16x8*)&XQb[tb + ln][0];
  bf16x8 xhi0 = *(const bf16x8*)&XQb[tb + ln][8];
  bf16x8 xlo1 = *(const bf16x8*)&XQb[tb + 16 + ln][0];
  bf16x8 xhi1 = *(const bf16x8*)&XQb[tb + 16 + ln][8];
#pragma unroll
  for (int kt = 0; kt < 8; ++kt) {
    int i = kt * 2 + (lg >> 1);
    float xqi0 = b2f(XQb[tb + ln][i]) * 0.0625f;
    float xqi1 = b2f(XQb[tb + 16 + ln][i]) * 0.0625f;
    bf16x8 sel0 = (lg & 1) ? xhi0 : xlo0;
    bf16x8 sel1 = (lg & 1) ? xhi1 : xlo1;
    bf16x8 qa0, qa1;
#pragma unroll
    for (int jj = 0; jj < 8; ++jj) {
      qa0[jj] = (short)f2b(xqi0 * b2f((unsigned short)sel0[jj]));
      qa1[jj] = (short)f2b(xqi1 * b2f((unsigned short)sel1[jj]));
    }
    int r0 = kt * 32 + lg * 8;
#pragma unroll
    for (int nt = 0; nt < 4; ++nt) {
      bf16x8 bp = *(const bf16x8*)&Sp[(size_t)(nt * 16 + ln) * 256 + r0];
      o[0][nt] = __builtin_amdgcn_mfma_f32_16x16x32_bf16(qa0, bp, o[0][nt], 0, 0, 0);
      o[1][nt] = __builtin_amdgcn_mfma_f32_16x16x32_bf16(qa1, bp, o[1][nt], 0, 0, 0);
    }
  }

  float zi2[2][4];
#pragma unroll
  for (int mt = 0; mt < 2; ++mt)
#pragma unroll
    for (int j = 0; j < 4; ++j) {
      int t = tb + mt * 16 + lg * 4 + j;
      float xqi = b2f(XQb[t][ln]);
      float p = 0.f;
#pragma unroll
      for (int jm = 0; jm < 16; ++jm) p += b2f(XQb[t][jm]) * mksh[jm * 16 + ln];
      p *= xqi;
      p += __shfl_xor(p, 1, 64);
      p += __shfl_xor(p, 2, 64);
      p += __shfl_xor(p, 4, 64);
      p += __shfl_xor(p, 8, 64);
      zi2[mt][j] = p * 0.0625f;
    }

  unsigned short* ob = OAB + ((size_t)(b * T_SEQ + c * CH)) * 1024 + h * 64;
#pragma unroll
  for (int mt = 0; mt < 2; ++mt)
#pragma unroll
    for (int j = 0; j < 4; ++j) {
      int t = tb + mt * 16 + lg * 4 + j;
      float inv = 1.0f / (zin[mt][j] + zi2[mt][j] + 1e-10f);
#pragma unroll
      for (int nt = 0; nt < 4; ++nt)
        ob[(size_t)t * 1024 + nt * 16 + ln] = f2b(o[mt][nt][j] * inv);
    }
}

// ---------------------------------------------------------------------------
extern "C" void kernel_launch(void* const* d_in, const int* in_sizes, int n_in,
                              void* d_out, int out_size, void* d_ws, size_t ws_size,
                              hipStream_t stream) {
  const float* hs    = (const float*)d_in[0];
  const float* Wq    = (const float*)d_in[1];
  const float* Wk    = (const float*)d_in[2];
  const float* Wv    = (const float*)d_in[3];
  const float* Wo    = (const float*)d_in[4];
  const float* gamma = (const float*)d_in[5];
  const float* beta  = (const float*)d_in[6];
  float* out = (float*)d_out;
  float* ws  = (float*)d_ws;

  float* QK = ws + QK_OFF;
  unsigned short* VTg   = (unsigned short*)(ws + VT_OFF);
  unsigned short* Sraw  = (unsigned short*)(ws + SRAW_OFF);
  unsigned short* Spre  = (unsigned short*)(ws + SPRE_OFF);
  float* Mk = ws + MK_OFF;
  unsigned short* OAB   = (unsigned short*)(ws + OAB_OFF);
  unsigned short* WQKVB = (unsigned short*)(ws + WQKV_OFF);
  unsigned short* WOB   = (unsigned short*)(ws + WO_OFF);
  unsigned short* HSB   = (unsigned short*)(ws + HSB_OFF);

  dim3 blk(256);
  conv_all<<<5376, blk, 0, stream>>>(hs, Wq, Wk, Wv, Wo, HSB, WQKVB, WOB);
  proj_gemm<<<768, blk, 0, stream>>>(HSB, WQKVB, QK, VTg);
  k_states<<<dim3(NCHUNK, NBH), blk, 0, stream>>>(QK, VTg, gamma, beta, Sraw, Mk);
  k_prefix<<<dim3(9, NBH), blk, 0, stream>>>(Sraw, Spre, Mk);
  k_attn_out<<<dim3(NCHUNK, NBH), blk, 0, stream>>>(QK, VTg, gamma, beta, Spre, Mk, OAB);
  out_gemm<<<512, blk, 0, stream>>>(OAB, WOB, out);
}